// Round 2
// baseline (516.599 us; speedup 1.0000x reference)
//
#include <hip/hip_runtime.h>
#include <cstdint>
#include <cstddef>

#define V_SIZE 50257
#define V_PAD  50432
#define NV4    (V_PAD/4)
#define SUBV   (NV4/8)
#define SIDEC  8192
#define D_DIM  1024
#define T_TOK  8192
#define NCHUNK 64
#define CCHUNK 128
#define NCAND  2048
#define NTILES 16
#define LOWR   32

typedef unsigned int  uint32;
typedef unsigned short u16;
typedef unsigned long long u64;
typedef __attribute__((ext_vector_type(8))) short short8;
typedef __attribute__((ext_vector_type(4))) float f32x4;

__device__ __forceinline__ u16 f2bf(float f){
  uint32 u = __float_as_uint(f);
  return (u16)((u + 0x7FFFu + ((u >> 16) & 1u)) >> 16);
}
__device__ __forceinline__ uint32 key_of(float f){
  uint32 b = __float_as_uint(f);
  return b ^ ((uint32)((int)b >> 31) | 0x80000000u);
}
__device__ __forceinline__ float sigscale(const float* lsc){
  return 100.f / (1.f + __expf(-lsc[0])) + 1.f;
}
__device__ __forceinline__ float wred_sum(float v){
  #pragma unroll
  for (int m = 32; m >= 1; m >>= 1) v += __shfl_xor(v, m, 64);
  return v;
}
__device__ __forceinline__ float wred_max(float v){
  #pragma unroll
  for (int m = 32; m >= 1; m >>= 1) v = fmaxf(v, __shfl_xor(v, m, 64));
  return v;
}
__device__ __forceinline__ void gload_lds16(const void* g, void* l){
  __builtin_amdgcn_global_load_lds(
      (const __attribute__((address_space(1))) uint32*)g,
      (__attribute__((address_space(3))) uint32*)l, 16, 0, 0);
}
__device__ __forceinline__ void load_row16(const float* base, int lane, float* f){
  const float4* s4 = (const float4*)(base + lane * 16);
  float4 t0 = s4[0], t1 = s4[1], t2 = s4[2], t3 = s4[3];
  f[0]=t0.x; f[1]=t0.y; f[2]=t0.z;  f[3]=t0.w;
  f[4]=t1.x; f[5]=t1.y; f[6]=t1.z;  f[7]=t1.w;
  f[8]=t2.x; f[9]=t2.y; f[10]=t2.z; f[11]=t2.w;
  f[12]=t3.x; f[13]=t3.y; f[14]=t3.z; f[15]=t3.w;
}
__device__ __forceinline__ void store_bf16x16(u16* dst_base, int lane, const float* f){
  uint32 pk[8];
  #pragma unroll
  for (int i=0;i<8;++i) pk[i] = (uint32)f2bf(f[2*i]) | ((uint32)f2bf(f[2*i+1]) << 16);
  uint4* d = (uint4*)(dst_base + lane * 16);
  d[0] = make_uint4(pk[0],pk[1],pk[2],pk[3]);
  d[1] = make_uint4(pk[4],pk[5],pk[6],pk[7]);
}

// ---------------- vocab prep: fp32 -> bf16 + inv norms (full & low32) ----------
__global__ void __launch_bounds__(256)
vocab_prep(const float* __restrict__ emb, u16* __restrict__ emb16,
           float* __restrict__ invn_f, float* __restrict__ invn_l)
{
  const int wid = threadIdx.x >> 6, lane = threadIdx.x & 63;
  const int v = blockIdx.x * 4 + wid;
  if (v >= V_SIZE) return;
  float f[16];
  load_row16(emb + (size_t)v * D_DIM, lane, f);
  float ss = 0.f;
  #pragma unroll
  for (int k=0;k<16;++k) ss += f[k]*f[k];
  float fullss = wred_sum(ss);
  float lowss  = wred_sum(lane < 2 ? ss : 0.f);   // lanes 0,1 own elems 0..31
  store_bf16x16(emb16 + (size_t)v * D_DIM, lane, f);
  if (lane == 0){
    invn_f[v] = 1.f / fmaxf(sqrtf(fullss), 1e-12f);
    invn_l[v] = 1.f / fmaxf(sqrtf(lowss),  1e-12f);
  }
}

// ---------------- token prep: bf16 h, inv norms, per-chunk mean of norm'd low h
__global__ void __launch_bounds__(256)
token_prep(const float* __restrict__ h, u16* __restrict__ h16,
           float* __restrict__ invh_f, float* __restrict__ invh_l,
           float* __restrict__ h_mean)
{
  const int nchunk = blockIdx.x;
  const int tid = threadIdx.x, lane = tid & 63, wid = tid >> 6;
  __shared__ float hm[LOWR];
  if (tid < LOWR) hm[tid] = 0.f;
  __syncthreads();
  for (int i = 0; i < 32; ++i){
    const int loc = wid*32 + i;
    const int tok = nchunk * CCHUNK + loc;
    float f[16];
    load_row16(h + (size_t)tok * D_DIM, lane, f);
    float ss = 0.f;
    #pragma unroll
    for (int k=0;k<16;++k) ss += f[k]*f[k];
    float fullss = wred_sum(ss);
    float lowss  = wred_sum(lane < 2 ? ss : 0.f);
    float invf = 1.f / fmaxf(sqrtf(fullss), 1e-12f);
    float invl = 1.f / fmaxf(sqrtf(lowss),  1e-12f);
    store_bf16x16(h16 + (size_t)tok * D_DIM, lane, f);
    if (lane == 0){ invh_f[tok] = invf; invh_l[tok] = invl; }
    if (lane < 2){
      #pragma unroll
      for (int k=0;k<16;++k) atomicAdd(&hm[lane*16 + k], f[k] * invl * (1.f/128.f));
    }
  }
  __syncthreads();
  if (tid < LOWR) h_mean[nchunk * LOWR + tid] = hm[tid];
}

// ---------------- scan: scan_logits[n][v] = h_mean[n] . normalize(emb[v,:32]) --
__global__ void __launch_bounds__(256)
scan_kernel(const float* __restrict__ emb, const float* __restrict__ invn_l,
            const float* __restrict__ h_mean, float* __restrict__ scan)
{
  __shared__ float hm[NCHUNK * LOWR];
  for (int i = threadIdx.x; i < NCHUNK * LOWR; i += 256) hm[i] = h_mean[i];
  __syncthreads();
  const int v = blockIdx.x * 256 + threadIdx.x;
  if (v >= V_SIZE){
    if (v < V_PAD)
      for (int nn = 0; nn < NCHUNK; ++nn) scan[(size_t)nn * V_PAD + v] = -3.4e38f;
    return;
  }
  float w[LOWR];
  const float4* s4 = (const float4*)(emb + (size_t)v * D_DIM);
  #pragma unroll
  for (int i=0;i<8;++i){
    float4 t = s4[i];
    w[4*i]=t.x; w[4*i+1]=t.y; w[4*i+2]=t.z; w[4*i+3]=t.w;
  }
  const float inv = invn_l[v];
  #pragma unroll
  for (int i=0;i<LOWR;++i) w[i] *= inv;
  for (int nn = 0; nn < NCHUNK; ++nn){
    float d = 0.f;
    #pragma unroll
    for (int l=0;l<LOWR;++l) d += w[l] * hm[nn*LOWR + l];
    scan[(size_t)nn * V_PAD + v] = d;
  }
}

// ---------------- topk stage A: 12-bit histogram per chunk ---------------------
__global__ void __launch_bounds__(256)
topk_hist(const float* __restrict__ scan, uint32* __restrict__ hist)
{
  const int nchunk = blockIdx.x, sub = blockIdx.y;
  const int tid = threadIdx.x;
  __shared__ uint32 h[4096];
  for (int i = tid; i < 4096; i += 256) h[i] = 0;
  __syncthreads();
  const float4* row = (const float4*)(scan + (size_t)nchunk * V_PAD) + sub * SUBV;
  for (int i = tid; i < SUBV; i += 256){
    float4 x = row[i];
    atomicAdd(&h[key_of(x.x) >> 20], 1u);
    atomicAdd(&h[key_of(x.y) >> 20], 1u);
    atomicAdd(&h[key_of(x.z) >> 20], 1u);
    atomicAdd(&h[key_of(x.w) >> 20], 1u);
  }
  __syncthreads();
  uint32* gh = hist + nchunk * 4096;
  for (int i = tid; i < 4096; i += 256) if (h[i]) atomicAdd(&gh[i], h[i]);
}

// ---------------- topk stage B: find threshold bin + greater-count -------------
__global__ void __launch_bounds__(256)
topk_thresh(const uint32* __restrict__ hist, uint32* __restrict__ thr)
{
  const int nchunk = blockIdx.x, tid = threadIdx.x;
  __shared__ uint32 h[4096];
  __shared__ uint32 ps[256];
  const uint32* gh = hist + nchunk * 4096;
  for (int i = tid; i < 4096; i += 256) h[i] = gh[i];
  __syncthreads();
  uint32 s = 0;
  #pragma unroll
  for (int k = 0; k < 16; ++k) s += h[tid*16 + k];
  ps[tid] = s;
  __syncthreads();
  if (tid == 0){
    uint32 cum = 0; int t = 255;
    for (; t > 0; --t){ if (cum + ps[t] >= NCAND) break; cum += ps[t]; }
    int b = t*16 + 15;
    for (; b > t*16; --b){ if (cum + h[b] >= NCAND) break; cum += h[b]; }
    thr[nchunk*2]   = (uint32)b;   // threshold bin
    thr[nchunk*2+1] = cum;         // count strictly greater (by bin)
  }
}

// ---------------- topk stage C: collect greater bins + side-buffer bin ---------
__global__ void __launch_bounds__(256)
topk_collect(const float* __restrict__ scan, const uint32* __restrict__ thr,
             uint32* __restrict__ cnt_gt, uint32* __restrict__ cnt_bin,
             u64* __restrict__ side,
             int* __restrict__ topidx, float* __restrict__ invc_f, float* __restrict__ invc_l,
             const float* __restrict__ invn_f, const float* __restrict__ invn_l)
{
  const int nchunk = blockIdx.x, sub = blockIdx.y;
  const int tid = threadIdx.x;
  const uint32 tb = thr[nchunk*2];
  const float4* row = (const float4*)(scan + (size_t)nchunk * V_PAD) + sub * SUBV;
  for (int i = tid; i < SUBV; i += 256){
    float4 x = row[i];
    const int vbase = (sub * SUBV + i) * 4;
    float vals[4] = {x.x, x.y, x.z, x.w};
    #pragma unroll
    for (int c = 0; c < 4; ++c){
      uint32 u = key_of(vals[c]);
      uint32 b = u >> 20;
      if (b < tb) continue;
      const int v = vbase + c;
      if (v >= V_SIZE) continue;
      if (b > tb){
        uint32 pos = atomicAdd(&cnt_gt[nchunk], 1u);
        int o = nchunk * NCAND + (int)pos;
        topidx[o] = v; invc_f[o] = invn_f[v]; invc_l[o] = invn_l[v];
      } else {
        uint32 p = atomicAdd(&cnt_bin[nchunk], 1u);
        if (p < SIDEC) side[(size_t)nchunk * SIDEC + p] = ((u64)(~u) << 32) | (uint32)v;
      }
    }
  }
}

// ---------------- topk stage D: exact in-LDS refine of threshold bin -----------
__global__ void __launch_bounds__(256)
topk_refine(const uint32* __restrict__ thr, const uint32* __restrict__ cnt_bin,
            const u64* __restrict__ side,
            int* __restrict__ topidx, float* __restrict__ invc_f, float* __restrict__ invc_l,
            const float* __restrict__ invn_f, const float* __restrict__ invn_l)
{
  const int nchunk = blockIdx.x, tid = threadIdx.x;
  __shared__ u64 sd[SIDEC];
  __shared__ uint32 h[256];
  __shared__ uint32 s_sel, s_cum, s_pos;
  const uint32 cgt = thr[nchunk*2+1];
  int n = (int)cnt_bin[nchunk]; if (n > SIDEC) n = SIDEC;
  uint32 r = NCAND - cgt; if ((int)r > n) r = (uint32)n;
  for (int i = tid; i < n; i += 256) sd[i] = side[(size_t)nchunk * SIDEC + i];
  if (tid == 0) s_pos = 0;
  __syncthreads();
  // r-th smallest u64 (= r-th best candidate; all values distinct since idx embedded)
  u64 pref = 0; uint32 rem = r;
  for (int by = 7; by >= 0; --by){
    if (tid < 256) h[tid] = 0;
    __syncthreads();
    const u64 pmask = (by == 7) ? 0ull : (~0ull << ((by+1)*8));
    for (int i = tid; i < n; i += 256){
      u64 x = sd[i];
      if ((x & pmask) == pref) atomicAdd(&h[(uint32)(x >> (by*8)) & 255u], 1u);
    }
    __syncthreads();
    if (tid == 0){
      uint32 cum = 0; int b = 0;
      for (; b < 255; ++b){ if (cum + h[b] >= rem) break; cum += h[b]; }
      s_sel = (uint32)b; s_cum = cum;
    }
    __syncthreads();
    pref |= ((u64)s_sel) << (by*8);
    rem -= s_cum;
    __syncthreads();
  }
  for (int i = tid; i < n; i += 256){
    u64 x = sd[i];
    if (x <= pref){
      uint32 p = atomicAdd(&s_pos, 1u);
      int v = (int)(uint32)x;
      int o = nchunk * NCAND + (int)(cgt + p);
      topidx[o] = v; invc_f[o] = invn_f[v]; invc_l[o] = invn_l[v];
    }
  }
}

// ---------------- bf16 MFMA GEMM (h x gathered cand rows) + fused partial LSE --
template<int KTOT, int BK>
__global__ void __launch_bounds__(256)
gemm_partial(const u16* __restrict__ h16, const u16* __restrict__ emb16,
             const int* __restrict__ topidx, const float* __restrict__ invh,
             const float* __restrict__ invc, const int* __restrict__ tgts,
             const float* __restrict__ lsc, float* __restrict__ partials)
{
  constexpr int NSTEP = KTOT / BK;
  constexpr int KK    = BK / 32;
  constexpr int LPR   = (BK * 2) / 16;  // lanes per staged row
  constexpr int RPC   = 64 / LPR;       // rows per global_load_lds call
  constexpr int CALLS = 32 / RPC;       // calls per wave (32 rows/wave)

  const int ntile = blockIdx.x, nchunk = blockIdx.y;
  const int tid = threadIdx.x, lane = tid & 63, wid = tid >> 6;
  const int wm = wid >> 1, wn = wid & 1;
  const int fq = lane >> 4, fr = lane & 15;

  __shared__ u16 As[CCHUNK * BK];
  __shared__ u16 Bs[CCHUNK * BK];
  __shared__ float s_invh[CCHUNK];
  __shared__ float s_invc[CCHUNK];
  __shared__ int   s_tgt[CCHUNK];
  __shared__ int   s_idx[CCHUNK];

  if (tid < CCHUNK){
    s_invh[tid] = invh[nchunk * CCHUNK + tid];
    s_tgt[tid]  = tgts[nchunk * CCHUNK + tid];
    int o = nchunk * NCAND + ntile * CCHUNK + tid;
    s_idx[tid]  = topidx[o];
    s_invc[tid] = invc[o];
  }

  const int rl = lane / LPR;
  const int cbyte = (lane % LPR) * 16;
  const char* aptr[CALLS];
  const char* bptr[CALLS];
  #pragma unroll
  for (int s = 0; s < CALLS; ++s){
    int row = wid * 32 + s * RPC + rl;
    aptr[s] = (const char*)h16 + ((size_t)(nchunk * CCHUNK + row)) * (D_DIM * 2) + cbyte;
    int cidx = topidx[nchunk * NCAND + ntile * CCHUNK + row];
    bptr[s] = (const char*)emb16 + (size_t)cidx * (D_DIM * 2) + cbyte;
  }

  f32x4 acc[4][4];
  #pragma unroll
  for (int m=0;m<4;++m)
    #pragma unroll
    for (int q=0;q<4;++q)
      acc[m][q] = (f32x4){0.f,0.f,0.f,0.f};

  for (int st = 0; st < NSTEP; ++st){
    const int koff = st * BK * 2;
    #pragma unroll
    for (int s = 0; s < CALLS; ++s){
      gload_lds16(aptr[s] + koff, (void*)&As[(wid*32 + s*RPC) * BK]);
      gload_lds16(bptr[s] + koff, (void*)&Bs[(wid*32 + s*RPC) * BK]);
    }
    __syncthreads();
    #pragma unroll
    for (int kk = 0; kk < KK; ++kk){
      const int ko = kk*32 + fq*8;
      short8 af[4], bf[4];
      #pragma unroll
      for (int m=0;m<4;++m) af[m] = *(const short8*)&As[(wm*64 + m*16 + fr)*BK + ko];
      #pragma unroll
      for (int q=0;q<4;++q) bf[q] = *(const short8*)&Bs[(wn*64 + q*16 + fr)*BK + ko];
      #pragma unroll
      for (int m=0;m<4;++m)
        #pragma unroll
        for (int q=0;q<4;++q)
          acc[m][q] = __builtin_amdgcn_mfma_f32_16x16x32_bf16(af[m], bf[q], acc[m][q], 0, 0, 0);
    }
    __syncthreads();
  }

  const float scale = sigscale(lsc);
  const float NEG = -__builtin_huge_valf();
  #pragma unroll
  for (int m=0;m<4;++m){
    #pragma unroll
    for (int j=0;j<4;++j){
      const int c = wm*64 + m*16 + fq*4 + j;
      const float ihs = s_invh[c] * scale;
      const int tg = s_tgt[c];
      float vals[4];
      #pragma unroll
      for (int q=0;q<4;++q){
        const int kl = wn*64 + q*16 + fr;
        float lg = acc[m][q][j] * ihs * s_invc[kl];
        vals[q] = (s_idx[kl] == tg) ? NEG : lg;
      }
      float lmax = fmaxf(fmaxf(vals[0], vals[1]), fmaxf(vals[2], vals[3]));
      #pragma unroll
      for (int ms=1; ms<16; ms<<=1) lmax = fmaxf(lmax, __shfl_xor(lmax, ms, 64));
      float se = 0.f;
      #pragma unroll
      for (int q=0;q<4;++q) se += __expf(vals[q] - lmax);
      #pragma unroll
      for (int ms=1; ms<16; ms<<=1) se += __shfl_xor(se, ms, 64);
      if (fr == 0){
        size_t pos = ((size_t)((nchunk*NTILES + ntile)*2 + wn) * CCHUNK + c) * 2;
        partials[pos]   = lmax;
        partials[pos+1] = se;
      }
    }
  }
}

// ---------------- merge partials + target term -> scalar loss ------------------
__global__ void __launch_bounds__(256)
merge_loss(const u16* __restrict__ h16, const u16* __restrict__ emb16,
           const int* __restrict__ tgts,
           const float* __restrict__ invh_f, const float* __restrict__ invh_l,
           const float* __restrict__ invn_f, const float* __restrict__ invn_l,
           const float* __restrict__ pm, const float* __restrict__ pa,
           const float* __restrict__ lsc, float* __restrict__ out)
{
  const int nchunk = blockIdx.x >> 2, quarter = blockIdx.x & 3;
  const int tid = threadIdx.x, lane = tid & 63, wid = tid >> 6;
  const float scale = sigscale(lsc);
  const float NEG = -__builtin_huge_valf();
  float wacc = 0.f;
  for (int i = 0; i < 8; ++i){
    const int loc = quarter*32 + wid*8 + i;
    const int tok = nchunk * CCHUNK + loc;
    const int t = tgts[tok];
    float part = 0.f;
    {
      const uint4* hp = (const uint4*)(h16 + (size_t)tok * D_DIM) + lane*2;
      const uint4* ep = (const uint4*)(emb16 + (size_t)t * D_DIM) + lane*2;
      uint4 hx = hp[0], hy = hp[1], ex = ep[0], ey = ep[1];
      uint32 hu[8] = {hx.x,hx.y,hx.z,hx.w,hy.x,hy.y,hy.z,hy.w};
      uint32 eu[8] = {ex.x,ex.y,ex.z,ex.w,ey.x,ey.y,ey.z,ey.w};
      #pragma unroll
      for (int k=0;k<8;++k){
        float h0 = __uint_as_float(hu[k] << 16);
        float h1 = __uint_as_float(hu[k] & 0xFFFF0000u);
        float e0 = __uint_as_float(eu[k] << 16);
        float e1 = __uint_as_float(eu[k] & 0xFFFF0000u);
        part += h0*e0 + h1*e1;
      }
    }
    float dfull = wred_sum(part);
    float dlow  = wred_sum(lane < 2 ? part : 0.f);
    float tful = dfull * invh_f[tok] * invn_f[t] * scale;
    float tlow = dlow  * invh_l[tok] * invn_l[t] * scale;

    float mi = NEG, si = 0.f, mia = NEG, sia = 0.f;
    if (lane < 32){
      size_t q = ((size_t)(nchunk*32 + lane) * CCHUNK + loc) * 2;
      mi  = pm[q]; si  = pm[q+1];
      mia = pa[q]; sia = pa[q+1];
    }
    float M  = wred_max(mi);
    float S  = wred_sum(lane < 32 ? si * __expf(mi - M) : 0.f);
    float M2 = fmaxf(M, tful);
    float lmain = __logf(S * __expf(M - M2) + __expf(tful - M2)) + M2 - tful;
    float Ma  = wred_max(mia);
    float Sa  = wred_sum(lane < 32 ? sia * __expf(mia - Ma) : 0.f);
    float M2a = fmaxf(Ma, tlow);
    float laux = __logf(Sa * __expf(Ma - M2a) + __expf(tlow - M2a)) + M2a - tlow;
    wacc += lmain + 0.2f * laux;
  }
  __shared__ float ws4[4];
  if (lane == 0) ws4[wid] = wacc;
  __syncthreads();
  if (tid == 0) atomicAdd(out, (ws4[0]+ws4[1]+ws4[2]+ws4[3]) * (1.f / (float)T_TOK));
}

// ---------------- host ---------------------------------------------------------
extern "C" void kernel_launch(void* const* d_in, const int* in_sizes, int n_in,
                              void* d_out, int out_size, void* d_ws, size_t ws_size,
                              hipStream_t stream)
{
  (void)in_sizes; (void)n_in;
  const float* h   = (const float*)d_in[0];
  const float* emb = (const float*)d_in[1];
  const float* lsc = (const float*)d_in[2];
  const int*   tgt = (const int*)d_in[3];
  float* out = (float*)d_out;

  uint8_t* p = (uint8_t*)d_ws;
  auto carve = [&](size_t n)->uint8_t*{
    uint8_t* r = p; p += (n + 255) & ~(size_t)255; return r;
  };
  u16*   emb16  = (u16*)  carve((size_t)V_SIZE * D_DIM * 2);
  float* invn_f = (float*)carve((size_t)V_SIZE * 4);
  float* invn_l = (float*)carve((size_t)V_SIZE * 4);
  u16*   h16    = (u16*)  carve((size_t)T_TOK * D_DIM * 2);
  float* invh_f = (float*)carve((size_t)T_TOK * 4);
  float* invh_l = (float*)carve((size_t)T_TOK * 4);
  float* h_mean = (float*)carve((size_t)NCHUNK * LOWR * 4);
  float* scan   = (float*)carve((size_t)NCHUNK * V_PAD * 4);
  int*   topidx = (int*)  carve((size_t)NCHUNK * NCAND * 4);
  float* invc_f = (float*)carve((size_t)NCHUNK * NCAND * 4);
  float* invc_l = (float*)carve((size_t)NCHUNK * NCAND * 4);
  float* pm     = (float*)carve((size_t)NCHUNK * 32 * CCHUNK * 2 * 4);
  float* pa     = (float*)carve((size_t)NCHUNK * 32 * CCHUNK * 2 * 4);
  // topk scratch (hist + counters carved contiguously -> single memset)
  uint8_t* zbase = p;
  uint32* hist    = (uint32*)carve((size_t)NCHUNK * 4096 * 4);
  uint32* cnt_gt  = (uint32*)carve((size_t)NCHUNK * 4);
  uint32* cnt_bin = (uint32*)carve((size_t)NCHUNK * 4);
  size_t zbytes = (size_t)(p - zbase);
  uint32* thr  = (uint32*)carve((size_t)NCHUNK * 2 * 4);
  u64*    side = (u64*)  carve((size_t)NCHUNK * SIDEC * 8);
  (void)ws_size;

  hipMemsetAsync(out, 0, (size_t)out_size * sizeof(float), stream);
  hipMemsetAsync(zbase, 0, zbytes, stream);
  vocab_prep<<<dim3((V_SIZE + 3) / 4), dim3(256), 0, stream>>>(emb, emb16, invn_f, invn_l);
  token_prep<<<dim3(NCHUNK), dim3(256), 0, stream>>>(h, h16, invh_f, invh_l, h_mean);
  scan_kernel<<<dim3(V_PAD / 256), dim3(256), 0, stream>>>(emb, invn_l, h_mean, scan);
  topk_hist<<<dim3(NCHUNK, 8), dim3(256), 0, stream>>>(scan, hist);
  topk_thresh<<<dim3(NCHUNK), dim3(256), 0, stream>>>(hist, thr);
  topk_collect<<<dim3(NCHUNK, 8), dim3(256), 0, stream>>>(
      scan, thr, cnt_gt, cnt_bin, side, topidx, invc_f, invc_l, invn_f, invn_l);
  topk_refine<<<dim3(NCHUNK), dim3(256), 0, stream>>>(
      thr, cnt_bin, side, topidx, invc_f, invc_l, invn_f, invn_l);
  gemm_partial<1024, 64><<<dim3(NTILES, NCHUNK), dim3(256), 0, stream>>>(
      h16, emb16, topidx, invh_f, invc_f, tgt, lsc, pm);
  gemm_partial<32, 32><<<dim3(NTILES, NCHUNK), dim3(256), 0, stream>>>(
      h16, emb16, topidx, invh_l, invc_l, tgt, lsc, pa);
  merge_loss<<<dim3(NCHUNK * 4), dim3(256), 0, stream>>>(
      h16, emb16, tgt, invh_f, invh_l, invn_f, invn_l, pm, pa, lsc, out);
}

// Round 3
// 301.183 us; speedup vs baseline: 1.7152x; 1.7152x over previous
//
#include <hip/hip_runtime.h>
#include <cstdint>
#include <cstddef>

#define V_SIZE 50257
#define V_PAD  50432
#define NV4    (V_PAD/4)
#define SUBV   (NV4/8)
#define SIDEC  8192
#define SIDE_PER 16384
#define D_DIM  1024
#define T_TOK  8192
#define NCHUNK 64
#define CCHUNK 128
#define NCAND  2048
#define NTILES 16
#define LOWR   32

typedef unsigned int  uint32;
typedef unsigned short u16;
typedef unsigned long long u64;
typedef __attribute__((ext_vector_type(8))) short short8;
typedef __attribute__((ext_vector_type(4))) float f32x4;

__device__ __forceinline__ u16 f2bf(float f){
  uint32 u = __float_as_uint(f);
  return (u16)((u + 0x7FFFu + ((u >> 16) & 1u)) >> 16);
}
__device__ __forceinline__ uint32 key_of(float f){
  uint32 b = __float_as_uint(f);
  return b ^ ((uint32)((int)b >> 31) | 0x80000000u);
}
__device__ __forceinline__ float sigscale(const float* lsc){
  return 100.f / (1.f + __expf(-lsc[0])) + 1.f;
}
__device__ __forceinline__ float wred_sum(float v){
  #pragma unroll
  for (int m = 32; m >= 1; m >>= 1) v += __shfl_xor(v, m, 64);
  return v;
}
__device__ __forceinline__ float wred_max(float v){
  #pragma unroll
  for (int m = 32; m >= 1; m >>= 1) v = fmaxf(v, __shfl_xor(v, m, 64));
  return v;
}
__device__ __forceinline__ void gload_lds16(const void* g, void* l){
  __builtin_amdgcn_global_load_lds(
      (const __attribute__((address_space(1))) uint32*)g,
      (__attribute__((address_space(3))) uint32*)l, 16, 0, 0);
}
__device__ __forceinline__ void load_row16(const float* base, int lane, float* f){
  const float4* s4 = (const float4*)(base + lane * 16);
  float4 t0 = s4[0], t1 = s4[1], t2 = s4[2], t3 = s4[3];
  f[0]=t0.x; f[1]=t0.y; f[2]=t0.z;  f[3]=t0.w;
  f[4]=t1.x; f[5]=t1.y; f[6]=t1.z;  f[7]=t1.w;
  f[8]=t2.x; f[9]=t2.y; f[10]=t2.z; f[11]=t2.w;
  f[12]=t3.x; f[13]=t3.y; f[14]=t3.z; f[15]=t3.w;
}
__device__ __forceinline__ void store_bf16x16(u16* dst_base, int lane, const float* f){
  uint32 pk[8];
  #pragma unroll
  for (int i=0;i<8;++i) pk[i] = (uint32)f2bf(f[2*i]) | ((uint32)f2bf(f[2*i+1]) << 16);
  uint4* d = (uint4*)(dst_base + lane * 16);
  d[0] = make_uint4(pk[0],pk[1],pk[2],pk[3]);
  d[1] = make_uint4(pk[4],pk[5],pk[6],pk[7]);
}

// ---------------- vocab prep: fp32 -> bf16 + inv norms (full & low32) ----------
__global__ void __launch_bounds__(256)
vocab_prep(const float* __restrict__ emb, u16* __restrict__ emb16,
           float* __restrict__ invn_f, float* __restrict__ invn_l)
{
  const int wid = threadIdx.x >> 6, lane = threadIdx.x & 63;
  const int v = blockIdx.x * 4 + wid;
  if (v >= V_SIZE) return;
  float f[16];
  load_row16(emb + (size_t)v * D_DIM, lane, f);
  float ss = 0.f;
  #pragma unroll
  for (int k=0;k<16;++k) ss += f[k]*f[k];
  float fullss = wred_sum(ss);
  float lowss  = wred_sum(lane < 2 ? ss : 0.f);   // lanes 0,1 own elems 0..31
  store_bf16x16(emb16 + (size_t)v * D_DIM, lane, f);
  if (lane == 0){
    invn_f[v] = 1.f / fmaxf(sqrtf(fullss), 1e-12f);
    invn_l[v] = 1.f / fmaxf(sqrtf(lowss),  1e-12f);
  }
}

// ---------------- token prep: bf16 h, inv norms, per-chunk mean of norm'd low h
__global__ void __launch_bounds__(256)
token_prep(const float* __restrict__ h, u16* __restrict__ h16,
           float* __restrict__ invh_f, float* __restrict__ invh_l,
           float* __restrict__ h_mean)
{
  const int nchunk = blockIdx.x;
  const int tid = threadIdx.x, lane = tid & 63, wid = tid >> 6;
  __shared__ float hm[LOWR];
  if (tid < LOWR) hm[tid] = 0.f;
  __syncthreads();
  for (int i = 0; i < 32; ++i){
    const int loc = wid*32 + i;
    const int tok = nchunk * CCHUNK + loc;
    float f[16];
    load_row16(h + (size_t)tok * D_DIM, lane, f);
    float ss = 0.f;
    #pragma unroll
    for (int k=0;k<16;++k) ss += f[k]*f[k];
    float fullss = wred_sum(ss);
    float lowss  = wred_sum(lane < 2 ? ss : 0.f);
    float invf = 1.f / fmaxf(sqrtf(fullss), 1e-12f);
    float invl = 1.f / fmaxf(sqrtf(lowss),  1e-12f);
    store_bf16x16(h16 + (size_t)tok * D_DIM, lane, f);
    if (lane == 0){ invh_f[tok] = invf; invh_l[tok] = invl; }
    if (lane < 2){
      #pragma unroll
      for (int k=0;k<16;++k) atomicAdd(&hm[lane*16 + k], f[k] * invl * (1.f/128.f));
    }
  }
  __syncthreads();
  if (tid < LOWR) h_mean[nchunk * LOWR + tid] = hm[tid];
}

// ---------------- scan: scan_logits[n][v] = h_mean[n] . normalize(emb[v,:32]) --
__global__ void __launch_bounds__(256)
scan_kernel(const float* __restrict__ emb, const float* __restrict__ invn_l,
            const float* __restrict__ h_mean, float* __restrict__ scan)
{
  __shared__ float hm[NCHUNK * LOWR];
  for (int i = threadIdx.x; i < NCHUNK * LOWR; i += 256) hm[i] = h_mean[i];
  __syncthreads();
  const int v = blockIdx.x * 256 + threadIdx.x;
  if (v >= V_SIZE){
    if (v < V_PAD)
      for (int nn = 0; nn < NCHUNK; ++nn) scan[(size_t)nn * V_PAD + v] = -3.4e38f;
    return;
  }
  float w[LOWR];
  const float4* s4 = (const float4*)(emb + (size_t)v * D_DIM);
  #pragma unroll
  for (int i=0;i<8;++i){
    float4 t = s4[i];
    w[4*i]=t.x; w[4*i+1]=t.y; w[4*i+2]=t.z; w[4*i+3]=t.w;
  }
  const float inv = invn_l[v];
  #pragma unroll
  for (int i=0;i<LOWR;++i) w[i] *= inv;
  for (int nn = 0; nn < NCHUNK; ++nn){
    float d = 0.f;
    #pragma unroll
    for (int l=0;l<LOWR;++l) d += w[l] * hm[nn*LOWR + l];
    scan[(size_t)nn * V_PAD + v] = d;
  }
}

// ---------------- topk stage A: LDS hist + in-kernel threshold -----------------
__global__ void __launch_bounds__(1024)
topk_prepass(const float* __restrict__ scan, uint32* __restrict__ thr)
{
  const int nchunk = blockIdx.x, tid = threadIdx.x;
  __shared__ uint32 h[4096];
  for (int i = tid; i < 4096; i += 1024) h[i] = 0;
  __syncthreads();
  const float4* row = (const float4*)(scan + (size_t)nchunk * V_PAD);
  for (int i = tid; i < NV4; i += 1024){
    float4 x = row[i];
    atomicAdd(&h[key_of(x.x) >> 20], 1u);
    atomicAdd(&h[key_of(x.y) >> 20], 1u);
    atomicAdd(&h[key_of(x.z) >> 20], 1u);
    atomicAdd(&h[key_of(x.w) >> 20], 1u);
  }
  __syncthreads();
  if (tid < 64){
    const int lane = tid;
    // coarse: 64 groups of 64 bins; suffix-sum across lanes (s non-increasing)
    uint32 c = 0;
    #pragma unroll 8
    for (int k = 0; k < 64; ++k) c += h[lane*64 + k];
    uint32 s = c;
    #pragma unroll
    for (int off = 1; off < 64; off <<= 1){
      uint32 t = __shfl_down(s, off, 64);
      if (lane + off < 64) s += t;
    }
    u64 m1 = __ballot(s >= NCAND);
    const int g = 63 - __builtin_clzll(m1);
    const uint32 cum = (g < 63) ? __shfl(s, g + 1, 64) : 0u;
    // fine within group g
    uint32 s2 = h[g*64 + lane];
    #pragma unroll
    for (int off = 1; off < 64; off <<= 1){
      uint32 t = __shfl_down(s2, off, 64);
      if (lane + off < 64) s2 += t;
    }
    u64 m2 = __ballot(cum + s2 >= NCAND);
    const int j = 63 - __builtin_clzll(m2);
    const uint32 cgt = cum + ((j < 63) ? __shfl(s2, j + 1, 64) : 0u);
    if (lane == 0){
      thr[nchunk*2]   = (uint32)(g*64 + j);  // threshold bin
      thr[nchunk*2+1] = cgt;                 // strictly-greater (by bin) count
    }
  }
}

// ---------------- topk stage B: LDS compaction, 2 global atomics per block -----
__global__ void __launch_bounds__(256)
topk_collect(const float* __restrict__ scan, const uint32* __restrict__ thr,
             uint32* __restrict__ cnt_gt, uint32* __restrict__ cnt_bin,
             u64* __restrict__ side,
             int* __restrict__ topidx, float* __restrict__ invc_f, float* __restrict__ invc_l,
             const float* __restrict__ invn_f, const float* __restrict__ invn_l)
{
  const int nchunk = blockIdx.x, sub = blockIdx.y;
  const int tid = threadIdx.x;
  __shared__ int gt_list[2048];
  __shared__ u64 sd_list[2048];
  __shared__ uint32 n_gt, n_sd, b_gt, b_sd;
  if (tid == 0){ n_gt = 0; n_sd = 0; }
  __syncthreads();
  const uint32 tb = thr[nchunk*2];
  const float4* row = (const float4*)(scan + (size_t)nchunk * V_PAD) + sub * SUBV;
  for (int i = tid; i < SUBV; i += 256){
    float4 x = row[i];
    const int vbase = (sub * SUBV + i) * 4;
    float vals[4] = {x.x, x.y, x.z, x.w};
    #pragma unroll
    for (int c = 0; c < 4; ++c){
      uint32 u = key_of(vals[c]);
      uint32 b = u >> 20;
      const int v = vbase + c;
      if (b < tb || v >= V_SIZE) continue;
      if (b > tb){
        uint32 p = atomicAdd(&n_gt, 1u);
        if (p < 2048) gt_list[p] = v;
      } else {
        uint32 p = atomicAdd(&n_sd, 1u);
        if (p < 2048) sd_list[p] = ((u64)(~u) << 32) | (uint32)v;
      }
    }
  }
  __syncthreads();
  if (tid == 0){
    uint32 ng = n_gt < 2048u ? n_gt : 2048u;
    uint32 ns = n_sd < 2048u ? n_sd : 2048u;
    b_gt = atomicAdd(&cnt_gt[nchunk*32], ng);   // counters padded: 1 line each
    b_sd = atomicAdd(&cnt_bin[nchunk*32], ns);
    n_gt = ng; n_sd = ns;
  }
  __syncthreads();
  const uint32 ng = n_gt, ns = n_sd, bg = b_gt, bs = b_sd;
  for (uint32 i = tid; i < ng; i += 256){
    const int v = gt_list[i];
    const int o = nchunk * NCAND + (int)(bg + i);
    topidx[o] = v; invc_f[o] = invn_f[v]; invc_l[o] = invn_l[v];
  }
  for (uint32 i = tid; i < ns; i += 256){
    const uint32 p = bs + i;
    if (p < SIDE_PER) side[(size_t)nchunk * SIDE_PER + p] = sd_list[i];
  }
}

// ---------------- topk stage C: exact in-LDS refine of threshold bin -----------
__global__ void __launch_bounds__(256)
topk_refine(const uint32* __restrict__ thr, const uint32* __restrict__ cnt_bin,
            const u64* __restrict__ side,
            int* __restrict__ topidx, float* __restrict__ invc_f, float* __restrict__ invc_l,
            const float* __restrict__ invn_f, const float* __restrict__ invn_l)
{
  const int nchunk = blockIdx.x, tid = threadIdx.x;
  __shared__ u64 sd[SIDEC];
  __shared__ uint32 h[256];
  __shared__ uint32 s_sel, s_cum, s_pos;
  const uint32 cgt = thr[nchunk*2+1];
  int n = (int)cnt_bin[nchunk*32]; if (n > SIDEC) n = SIDEC;
  uint32 r = NCAND - cgt; if ((int)r > n) r = (uint32)n;
  for (int i = tid; i < n; i += 256) sd[i] = side[(size_t)nchunk * SIDE_PER + i];
  if (tid == 0) s_pos = 0;
  __syncthreads();
  // r-th smallest u64 (= r-th best candidate; all values distinct since idx embedded)
  u64 pref = 0; uint32 rem = r;
  for (int by = 7; by >= 0; --by){
    if (tid < 256) h[tid] = 0;
    __syncthreads();
    const u64 pmask = (by == 7) ? 0ull : (~0ull << ((by+1)*8));
    for (int i = tid; i < n; i += 256){
      u64 x = sd[i];
      if ((x & pmask) == pref) atomicAdd(&h[(uint32)(x >> (by*8)) & 255u], 1u);
    }
    __syncthreads();
    if (tid == 0){
      uint32 cum = 0; int b = 0;
      for (; b < 255; ++b){ if (cum + h[b] >= rem) break; cum += h[b]; }
      s_sel = (uint32)b; s_cum = cum;
    }
    __syncthreads();
    pref |= ((u64)s_sel) << (by*8);
    rem -= s_cum;
    __syncthreads();
  }
  for (int i = tid; i < n; i += 256){
    u64 x = sd[i];
    if (x <= pref){
      uint32 p = atomicAdd(&s_pos, 1u);
      int v = (int)(uint32)x;
      int o = nchunk * NCAND + (int)(cgt + p);
      topidx[o] = v; invc_f[o] = invn_f[v]; invc_l[o] = invn_l[v];
    }
  }
}

// ---------------- bf16 MFMA GEMM (h x gathered cand rows) + fused partial LSE --
template<int KTOT, int BK>
__global__ void __launch_bounds__(256)
gemm_partial(const u16* __restrict__ h16, const u16* __restrict__ emb16,
             const int* __restrict__ topidx, const float* __restrict__ invh,
             const float* __restrict__ invc, const int* __restrict__ tgts,
             const float* __restrict__ lsc, float* __restrict__ partials)
{
  constexpr int NSTEP = KTOT / BK;
  constexpr int KK    = BK / 32;
  constexpr int LPR   = (BK * 2) / 16;  // lanes per staged row
  constexpr int RPC   = 64 / LPR;       // rows per global_load_lds call
  constexpr int CALLS = 32 / RPC;       // calls per wave (32 rows/wave)

  const int ntile = blockIdx.x, nchunk = blockIdx.y;
  const int tid = threadIdx.x, lane = tid & 63, wid = tid >> 6;
  const int wm = wid >> 1, wn = wid & 1;
  const int fq = lane >> 4, fr = lane & 15;

  __shared__ u16 As[CCHUNK * BK];
  __shared__ u16 Bs[CCHUNK * BK];
  __shared__ float s_invh[CCHUNK];
  __shared__ float s_invc[CCHUNK];
  __shared__ int   s_tgt[CCHUNK];
  __shared__ int   s_idx[CCHUNK];

  if (tid < CCHUNK){
    s_invh[tid] = invh[nchunk * CCHUNK + tid];
    s_tgt[tid]  = tgts[nchunk * CCHUNK + tid];
    int o = nchunk * NCAND + ntile * CCHUNK + tid;
    s_idx[tid]  = topidx[o];
    s_invc[tid] = invc[o];
  }

  const int rl = lane / LPR;
  const int cbyte = (lane % LPR) * 16;
  const char* aptr[CALLS];
  const char* bptr[CALLS];
  #pragma unroll
  for (int s = 0; s < CALLS; ++s){
    int row = wid * 32 + s * RPC + rl;
    aptr[s] = (const char*)h16 + ((size_t)(nchunk * CCHUNK + row)) * (D_DIM * 2) + cbyte;
    int cidx = topidx[nchunk * NCAND + ntile * CCHUNK + row];
    bptr[s] = (const char*)emb16 + (size_t)cidx * (D_DIM * 2) + cbyte;
  }

  f32x4 acc[4][4];
  #pragma unroll
  for (int m=0;m<4;++m)
    #pragma unroll
    for (int q=0;q<4;++q)
      acc[m][q] = (f32x4){0.f,0.f,0.f,0.f};

  for (int st = 0; st < NSTEP; ++st){
    const int koff = st * BK * 2;
    #pragma unroll
    for (int s = 0; s < CALLS; ++s){
      gload_lds16(aptr[s] + koff, (void*)&As[(wid*32 + s*RPC) * BK]);
      gload_lds16(bptr[s] + koff, (void*)&Bs[(wid*32 + s*RPC) * BK]);
    }
    __syncthreads();
    #pragma unroll
    for (int kk = 0; kk < KK; ++kk){
      const int ko = kk*32 + fq*8;
      short8 af[4], bf[4];
      #pragma unroll
      for (int m=0;m<4;++m) af[m] = *(const short8*)&As[(wm*64 + m*16 + fr)*BK + ko];
      #pragma unroll
      for (int q=0;q<4;++q) bf[q] = *(const short8*)&Bs[(wn*64 + q*16 + fr)*BK + ko];
      #pragma unroll
      for (int m=0;m<4;++m)
        #pragma unroll
        for (int q=0;q<4;++q)
          acc[m][q] = __builtin_amdgcn_mfma_f32_16x16x32_bf16(af[m], bf[q], acc[m][q], 0, 0, 0);
    }
    __syncthreads();
  }

  const float scale = sigscale(lsc);
  const float NEG = -__builtin_huge_valf();
  #pragma unroll
  for (int m=0;m<4;++m){
    #pragma unroll
    for (int j=0;j<4;++j){
      const int c = wm*64 + m*16 + fq*4 + j;
      const float ihs = s_invh[c] * scale;
      const int tg = s_tgt[c];
      float vals[4];
      #pragma unroll
      for (int q=0;q<4;++q){
        const int kl = wn*64 + q*16 + fr;
        float lg = acc[m][q][j] * ihs * s_invc[kl];
        vals[q] = (s_idx[kl] == tg) ? NEG : lg;
      }
      float lmax = fmaxf(fmaxf(vals[0], vals[1]), fmaxf(vals[2], vals[3]));
      #pragma unroll
      for (int ms=1; ms<16; ms<<=1) lmax = fmaxf(lmax, __shfl_xor(lmax, ms, 64));
      float se = 0.f;
      #pragma unroll
      for (int q=0;q<4;++q) se += __expf(vals[q] - lmax);
      #pragma unroll
      for (int ms=1; ms<16; ms<<=1) se += __shfl_xor(se, ms, 64);
      if (fr == 0){
        size_t pos = ((size_t)((nchunk*NTILES + ntile)*2 + wn) * CCHUNK + c) * 2;
        partials[pos]   = lmax;
        partials[pos+1] = se;
      }
    }
  }
}

// ---------------- merge partials + target term -> scalar loss ------------------
__global__ void __launch_bounds__(256)
merge_loss(const u16* __restrict__ h16, const u16* __restrict__ emb16,
           const int* __restrict__ tgts,
           const float* __restrict__ invh_f, const float* __restrict__ invh_l,
           const float* __restrict__ invn_f, const float* __restrict__ invn_l,
           const float* __restrict__ pm, const float* __restrict__ pa,
           const float* __restrict__ lsc, float* __restrict__ out)
{
  const int nchunk = blockIdx.x >> 2, quarter = blockIdx.x & 3;
  const int tid = threadIdx.x, lane = tid & 63, wid = tid >> 6;
  const float scale = sigscale(lsc);
  const float NEG = -__builtin_huge_valf();
  float wacc = 0.f;
  for (int i = 0; i < 8; ++i){
    const int loc = quarter*32 + wid*8 + i;
    const int tok = nchunk * CCHUNK + loc;
    const int t = tgts[tok];
    float part = 0.f;
    {
      const uint4* hp = (const uint4*)(h16 + (size_t)tok * D_DIM) + lane*2;
      const uint4* ep = (const uint4*)(emb16 + (size_t)t * D_DIM) + lane*2;
      uint4 hx = hp[0], hy = hp[1], ex = ep[0], ey = ep[1];
      uint32 hu[8] = {hx.x,hx.y,hx.z,hx.w,hy.x,hy.y,hy.z,hy.w};
      uint32 eu[8] = {ex.x,ex.y,ex.z,ex.w,ey.x,ey.y,ey.z,ey.w};
      #pragma unroll
      for (int k=0;k<8;++k){
        float h0 = __uint_as_float(hu[k] << 16);
        float h1 = __uint_as_float(hu[k] & 0xFFFF0000u);
        float e0 = __uint_as_float(eu[k] << 16);
        float e1 = __uint_as_float(eu[k] & 0xFFFF0000u);
        part += h0*e0 + h1*e1;
      }
    }
    float dfull = wred_sum(part);
    float dlow  = wred_sum(lane < 2 ? part : 0.f);
    float tful = dfull * invh_f[tok] * invn_f[t] * scale;
    float tlow = dlow  * invh_l[tok] * invn_l[t] * scale;

    float mi = NEG, si = 0.f, mia = NEG, sia = 0.f;
    if (lane < 32){
      size_t q = ((size_t)(nchunk*32 + lane) * CCHUNK + loc) * 2;
      mi  = pm[q]; si  = pm[q+1];
      mia = pa[q]; sia = pa[q+1];
    }
    float M  = wred_max(mi);
    float S  = wred_sum(lane < 32 ? si * __expf(mi - M) : 0.f);
    float M2 = fmaxf(M, tful);
    float lmain = __logf(S * __expf(M - M2) + __expf(tful - M2)) + M2 - tful;
    float Ma  = wred_max(mia);
    float Sa  = wred_sum(lane < 32 ? sia * __expf(mia - Ma) : 0.f);
    float M2a = fmaxf(Ma, tlow);
    float laux = __logf(Sa * __expf(Ma - M2a) + __expf(tlow - M2a)) + M2a - tlow;
    wacc += lmain + 0.2f * laux;
  }
  __shared__ float ws4[4];
  if (lane == 0) ws4[wid] = wacc;
  __syncthreads();
  if (tid == 0) atomicAdd(out, (ws4[0]+ws4[1]+ws4[2]+ws4[3]) * (1.f / (float)T_TOK));
}

// ---------------- host ---------------------------------------------------------
extern "C" void kernel_launch(void* const* d_in, const int* in_sizes, int n_in,
                              void* d_out, int out_size, void* d_ws, size_t ws_size,
                              hipStream_t stream)
{
  (void)in_sizes; (void)n_in;
  const float* h   = (const float*)d_in[0];
  const float* emb = (const float*)d_in[1];
  const float* lsc = (const float*)d_in[2];
  const int*   tgt = (const int*)d_in[3];
  float* out = (float*)d_out;

  uint8_t* p = (uint8_t*)d_ws;
  auto carve = [&](size_t n)->uint8_t*{
    uint8_t* r = p; p += (n + 255) & ~(size_t)255; return r;
  };
  u16*   emb16  = (u16*)  carve((size_t)V_SIZE * D_DIM * 2);
  float* invn_f = (float*)carve((size_t)V_SIZE * 4);
  float* invn_l = (float*)carve((size_t)V_SIZE * 4);
  u16*   h16    = (u16*)  carve((size_t)T_TOK * D_DIM * 2);
  float* invh_f = (float*)carve((size_t)T_TOK * 4);
  float* invh_l = (float*)carve((size_t)T_TOK * 4);
  float* h_mean = (float*)carve((size_t)NCHUNK * LOWR * 4);
  float* scan   = (float*)carve((size_t)NCHUNK * V_PAD * 4);
  int*   topidx = (int*)  carve((size_t)NCHUNK * NCAND * 4);
  float* invc_f = (float*)carve((size_t)NCHUNK * NCAND * 4);
  float* invc_l = (float*)carve((size_t)NCHUNK * NCAND * 4);
  float* pm     = (float*)carve((size_t)NCHUNK * 32 * CCHUNK * 2 * 4);
  float* pa     = (float*)carve((size_t)NCHUNK * 32 * CCHUNK * 2 * 4);
  // topk scratch: padded counters (one 128B line per chunk), contiguous memset
  uint8_t* zbase = p;
  uint32* cnt_gt  = (uint32*)carve((size_t)NCHUNK * 32 * 4);
  uint32* cnt_bin = (uint32*)carve((size_t)NCHUNK * 32 * 4);
  size_t zbytes = (size_t)(p - zbase);
  uint32* thr  = (uint32*)carve((size_t)NCHUNK * 2 * 4);
  u64*    side = (u64*)  carve((size_t)NCHUNK * SIDE_PER * 8);
  (void)ws_size;

  hipMemsetAsync(out, 0, (size_t)out_size * sizeof(float), stream);
  hipMemsetAsync(zbase, 0, zbytes, stream);
  vocab_prep<<<dim3((V_SIZE + 3) / 4), dim3(256), 0, stream>>>(emb, emb16, invn_f, invn_l);
  token_prep<<<dim3(NCHUNK), dim3(256), 0, stream>>>(h, h16, invh_f, invh_l, h_mean);
  scan_kernel<<<dim3(V_PAD / 256), dim3(256), 0, stream>>>(emb, invn_l, h_mean, scan);
  topk_prepass<<<dim3(NCHUNK), dim3(1024), 0, stream>>>(scan, thr);
  topk_collect<<<dim3(NCHUNK, 8), dim3(256), 0, stream>>>(
      scan, thr, cnt_gt, cnt_bin, side, topidx, invc_f, invc_l, invn_f, invn_l);
  topk_refine<<<dim3(NCHUNK), dim3(256), 0, stream>>>(
      thr, cnt_bin, side, topidx, invc_f, invc_l, invn_f, invn_l);
  gemm_partial<1024, 64><<<dim3(NTILES, NCHUNK), dim3(256), 0, stream>>>(
      h16, emb16, topidx, invh_f, invc_f, tgt, lsc, pm);
  gemm_partial<32, 32><<<dim3(NTILES, NCHUNK), dim3(256), 0, stream>>>(
      h16, emb16, topidx, invh_l, invc_l, tgt, lsc, pa);
  merge_loss<<<dim3(NCHUNK * 4), dim3(256), 0, stream>>>(
      h16, emb16, tgt, invh_f, invh_l, invn_f, invn_l, pm, pa, lsc, out);
}

// Round 4
// 265.750 us; speedup vs baseline: 1.9439x; 1.1333x over previous
//
#include <hip/hip_runtime.h>
#include <cstdint>
#include <cstddef>

#define V_SIZE 50257
#define V_PAD  50432
#define NV4    (V_PAD/4)
#define SIDEC  8192
#define SIDE_PER 16384
#define D_DIM  1024
#define T_TOK  8192
#define NCHUNK 64
#define CCHUNK 128
#define NCAND  2048
#define NTILES 16
#define LOWR   32

typedef unsigned int  uint32;
typedef unsigned short u16;
typedef unsigned long long u64;
typedef __attribute__((ext_vector_type(8))) short short8;
typedef __attribute__((ext_vector_type(4))) float f32x4;

__device__ __forceinline__ u16 f2bf(float f){
  uint32 u = __float_as_uint(f);
  return (u16)((u + 0x7FFFu + ((u >> 16) & 1u)) >> 16);
}
__device__ __forceinline__ uint32 key_of(float f){
  uint32 b = __float_as_uint(f);
  return b ^ ((uint32)((int)b >> 31) | 0x80000000u);
}
__device__ __forceinline__ float sigscale(const float* lsc){
  return 100.f / (1.f + __expf(-lsc[0])) + 1.f;
}
__device__ __forceinline__ float wred_sum(float v){
  #pragma unroll
  for (int m = 32; m >= 1; m >>= 1) v += __shfl_xor(v, m, 64);
  return v;
}
__device__ __forceinline__ float wred_max(float v){
  #pragma unroll
  for (int m = 32; m >= 1; m >>= 1) v = fmaxf(v, __shfl_xor(v, m, 64));
  return v;
}
__device__ __forceinline__ void gload_lds16(const void* g, void* l){
  __builtin_amdgcn_global_load_lds(
      (const __attribute__((address_space(1))) uint32*)g,
      (__attribute__((address_space(3))) uint32*)l, 16, 0, 0);
}
__device__ __forceinline__ void load_row16(const float* base, int lane, float* f){
  const float4* s4 = (const float4*)(base + lane * 16);
  float4 t0 = s4[0], t1 = s4[1], t2 = s4[2], t3 = s4[3];
  f[0]=t0.x; f[1]=t0.y; f[2]=t0.z;  f[3]=t0.w;
  f[4]=t1.x; f[5]=t1.y; f[6]=t1.z;  f[7]=t1.w;
  f[8]=t2.x; f[9]=t2.y; f[10]=t2.z; f[11]=t2.w;
  f[12]=t3.x; f[13]=t3.y; f[14]=t3.z; f[15]=t3.w;
}
__device__ __forceinline__ void store_bf16x16(u16* dst_base, int lane, const float* f){
  uint32 pk[8];
  #pragma unroll
  for (int i=0;i<8;++i) pk[i] = (uint32)f2bf(f[2*i]) | ((uint32)f2bf(f[2*i+1]) << 16);
  uint4* d = (uint4*)(dst_base + lane * 16);
  d[0] = make_uint4(pk[0],pk[1],pk[2],pk[3]);
  d[1] = make_uint4(pk[4],pk[5],pk[6],pk[7]);
}

// ---------------- vocab prep: fp32 -> bf16 + inv norms (full & low32) ----------
__global__ void __launch_bounds__(256)
vocab_prep(const float* __restrict__ emb, u16* __restrict__ emb16,
           float* __restrict__ invn_f, float* __restrict__ invn_l)
{
  const int wid = threadIdx.x >> 6, lane = threadIdx.x & 63;
  const int v = blockIdx.x * 4 + wid;
  if (v >= V_SIZE) return;
  float f[16];
  load_row16(emb + (size_t)v * D_DIM, lane, f);
  float ss = 0.f;
  #pragma unroll
  for (int k=0;k<16;++k) ss += f[k]*f[k];
  float fullss = wred_sum(ss);
  float lowss  = wred_sum(lane < 2 ? ss : 0.f);   // lanes 0,1 own elems 0..31
  store_bf16x16(emb16 + (size_t)v * D_DIM, lane, f);
  if (lane == 0){
    invn_f[v] = 1.f / fmaxf(sqrtf(fullss), 1e-12f);
    invn_l[v] = 1.f / fmaxf(sqrtf(lowss),  1e-12f);
  }
}

// ---------------- token prep (512 blocks): bf16 h, inv norms, mean partials ----
__global__ void __launch_bounds__(256)
token_prep(const float* __restrict__ h, u16* __restrict__ h16,
           float* __restrict__ invh_f, float* __restrict__ invh_l,
           float* __restrict__ hpart, float* __restrict__ out)
{
  const int nchunk = blockIdx.x, sub = blockIdx.y;
  const int tid = threadIdx.x, lane = tid & 63, wid = tid >> 6;
  if (nchunk == 0 && sub == 0 && tid == 0) out[0] = 0.f;  // zero loss accumulator
  __shared__ float hm[LOWR];
  if (tid < LOWR) hm[tid] = 0.f;
  __syncthreads();
  for (int i = 0; i < 4; ++i){
    const int loc = sub*16 + wid*4 + i;
    const int tok = nchunk * CCHUNK + loc;
    float f[16];
    load_row16(h + (size_t)tok * D_DIM, lane, f);
    float ss = 0.f;
    #pragma unroll
    for (int k=0;k<16;++k) ss += f[k]*f[k];
    float fullss = wred_sum(ss);
    float lowss  = wred_sum(lane < 2 ? ss : 0.f);
    float invf = 1.f / fmaxf(sqrtf(fullss), 1e-12f);
    float invl = 1.f / fmaxf(sqrtf(lowss),  1e-12f);
    store_bf16x16(h16 + (size_t)tok * D_DIM, lane, f);
    if (lane == 0){ invh_f[tok] = invf; invh_l[tok] = invl; }
    if (lane < 2){
      #pragma unroll
      for (int k=0;k<16;++k) atomicAdd(&hm[lane*16 + k], f[k] * invl * (1.f/128.f));
    }
  }
  __syncthreads();
  if (tid < LOWR) hpart[(size_t)(nchunk*8 + sub) * LOWR + tid] = hm[tid];
}

// ---------------- scan: scan_logits[n][v] = h_mean[n] . normalize(emb[v,:32]) --
__global__ void __launch_bounds__(256)
scan_kernel(const float* __restrict__ emb, const float* __restrict__ invn_l,
            const float* __restrict__ hpart, float* __restrict__ scan)
{
  __shared__ float hm[NCHUNK * LOWR];
  for (int i = threadIdx.x; i < NCHUNK * LOWR; i += 256){
    const int nn = i >> 5, l = i & 31;
    float s = 0.f;
    #pragma unroll
    for (int p = 0; p < 8; ++p) s += hpart[(size_t)(nn*8 + p) * LOWR + l];
    hm[i] = s;
  }
  __syncthreads();
  const int v = blockIdx.x * 256 + threadIdx.x;
  if (v >= V_SIZE){
    if (v < V_PAD)
      for (int nn = 0; nn < NCHUNK; ++nn) scan[(size_t)nn * V_PAD + v] = -3.4e38f;
    return;
  }
  float w[LOWR];
  const float4* s4 = (const float4*)(emb + (size_t)v * D_DIM);
  #pragma unroll
  for (int i=0;i<8;++i){
    float4 t = s4[i];
    w[4*i]=t.x; w[4*i+1]=t.y; w[4*i+2]=t.z; w[4*i+3]=t.w;
  }
  const float inv = invn_l[v];
  #pragma unroll
  for (int i=0;i<LOWR;++i) w[i] *= inv;
  for (int nn = 0; nn < NCHUNK; ++nn){
    float d = 0.f;
    #pragma unroll
    for (int l=0;l<LOWR;++l) d += w[l] * hm[nn*LOWR + l];
    scan[(size_t)nn * V_PAD + v] = d;
  }
}

// ---------------- topk stage A: LDS hist + in-kernel threshold -----------------
__global__ void __launch_bounds__(1024)
topk_prepass(const float* __restrict__ scan, uint32* __restrict__ thr,
             uint32* __restrict__ cnt_gt, uint32* __restrict__ cnt_bin)
{
  const int nchunk = blockIdx.x, tid = threadIdx.x;
  if (tid == 0){ cnt_gt[nchunk*32] = 0u; cnt_bin[nchunk*32] = 0u; }
  __shared__ uint32 h[4096];
  for (int i = tid; i < 4096; i += 1024) h[i] = 0;
  __syncthreads();
  const float4* row = (const float4*)(scan + (size_t)nchunk * V_PAD);
  for (int i = tid; i < NV4; i += 1024){
    float4 x = row[i];
    atomicAdd(&h[key_of(x.x) >> 20], 1u);
    atomicAdd(&h[key_of(x.y) >> 20], 1u);
    atomicAdd(&h[key_of(x.z) >> 20], 1u);
    atomicAdd(&h[key_of(x.w) >> 20], 1u);
  }
  __syncthreads();
  if (tid < 64){
    const int lane = tid;
    uint32 c = 0;
    #pragma unroll 8
    for (int k = 0; k < 64; ++k) c += h[lane*64 + k];
    uint32 s = c;
    #pragma unroll
    for (int off = 1; off < 64; off <<= 1){
      uint32 t = __shfl_down(s, off, 64);
      if (lane + off < 64) s += t;
    }
    u64 m1 = __ballot(s >= NCAND);
    const int g = 63 - __builtin_clzll(m1);
    const uint32 cum = (g < 63) ? __shfl(s, g + 1, 64) : 0u;
    uint32 s2 = h[g*64 + lane];
    #pragma unroll
    for (int off = 1; off < 64; off <<= 1){
      uint32 t = __shfl_down(s2, off, 64);
      if (lane + off < 64) s2 += t;
    }
    u64 m2 = __ballot(cum + s2 >= NCAND);
    const int j = 63 - __builtin_clzll(m2);
    const uint32 cgt = cum + ((j < 63) ? __shfl(s2, j + 1, 64) : 0u);
    if (lane == 0){
      thr[nchunk*2]   = (uint32)(g*64 + j);
      thr[nchunk*2+1] = cgt;
    }
  }
}

// ---------------- topk stage B: LDS compaction, 2 global atomics per block -----
__global__ void __launch_bounds__(256)
topk_collect(const float* __restrict__ scan, const uint32* __restrict__ thr,
             uint32* __restrict__ cnt_gt, uint32* __restrict__ cnt_bin,
             u64* __restrict__ side,
             int* __restrict__ topidx, float* __restrict__ invc_f, float* __restrict__ invc_l,
             const float* __restrict__ invn_f, const float* __restrict__ invn_l)
{
  const int nchunk = blockIdx.x, sub = blockIdx.y;
  const int tid = threadIdx.x;
  __shared__ int gt_list[2048];
  __shared__ u64 sd_list[2048];
  __shared__ uint32 n_gt, n_sd, b_gt, b_sd;
  if (tid == 0){ n_gt = 0; n_sd = 0; }
  __syncthreads();
  const uint32 tb = thr[nchunk*2];
  const float4* row = (const float4*)(scan + (size_t)nchunk * V_PAD) + sub * (NV4/8);
  for (int i = tid; i < NV4/8; i += 256){
    float4 x = row[i];
    const int vbase = (sub * (NV4/8) + i) * 4;
    float vals[4] = {x.x, x.y, x.z, x.w};
    #pragma unroll
    for (int c = 0; c < 4; ++c){
      uint32 u = key_of(vals[c]);
      uint32 b = u >> 20;
      const int v = vbase + c;
      if (b < tb || v >= V_SIZE) continue;
      if (b > tb){
        uint32 p = atomicAdd(&n_gt, 1u);
        if (p < 2048) gt_list[p] = v;
      } else {
        uint32 p = atomicAdd(&n_sd, 1u);
        if (p < 2048) sd_list[p] = ((u64)(~u) << 32) | (uint32)v;
      }
    }
  }
  __syncthreads();
  if (tid == 0){
    uint32 ng = n_gt < 2048u ? n_gt : 2048u;
    uint32 ns = n_sd < 2048u ? n_sd : 2048u;
    b_gt = atomicAdd(&cnt_gt[nchunk*32], ng);
    b_sd = atomicAdd(&cnt_bin[nchunk*32], ns);
    n_gt = ng; n_sd = ns;
  }
  __syncthreads();
  const uint32 ng = n_gt, ns = n_sd, bg = b_gt, bs = b_sd;
  for (uint32 i = tid; i < ng; i += 256){
    const int v = gt_list[i];
    const int o = nchunk * NCAND + (int)(bg + i);
    topidx[o] = v; invc_f[o] = invn_f[v]; invc_l[o] = invn_l[v];
  }
  for (uint32 i = tid; i < ns; i += 256){
    const uint32 p = bs + i;
    if (p < SIDE_PER) side[(size_t)nchunk * SIDE_PER + p] = sd_list[i];
  }
}

// ---------------- topk stage C: exact in-LDS refine of threshold bin -----------
__global__ void __launch_bounds__(256)
topk_refine(const uint32* __restrict__ thr, const uint32* __restrict__ cnt_bin,
            const u64* __restrict__ side,
            int* __restrict__ topidx, float* __restrict__ invc_f, float* __restrict__ invc_l,
            const float* __restrict__ invn_f, const float* __restrict__ invn_l)
{
  const int nchunk = blockIdx.x, tid = threadIdx.x;
  __shared__ u64 sd[SIDEC];
  __shared__ uint32 h[256];
  __shared__ uint32 s_sel, s_cum, s_pos;
  const uint32 cgt = thr[nchunk*2+1];
  int n = (int)cnt_bin[nchunk*32]; if (n > SIDEC) n = SIDEC;
  uint32 r = NCAND - cgt; if ((int)r > n) r = (uint32)n;
  for (int i = tid; i < n; i += 256) sd[i] = side[(size_t)nchunk * SIDE_PER + i];
  if (tid == 0) s_pos = 0;
  __syncthreads();
  u64 pref = 0; uint32 rem = r;
  for (int by = 7; by >= 0; --by){
    if (tid < 256) h[tid] = 0;
    __syncthreads();
    const u64 pmask = (by == 7) ? 0ull : (~0ull << ((by+1)*8));
    for (int i = tid; i < n; i += 256){
      u64 x = sd[i];
      if ((x & pmask) == pref) atomicAdd(&h[(uint32)(x >> (by*8)) & 255u], 1u);
    }
    __syncthreads();
    if (tid == 0){
      uint32 cum = 0; int b = 0;
      for (; b < 255; ++b){ if (cum + h[b] >= rem) break; cum += h[b]; }
      s_sel = (uint32)b; s_cum = cum;
    }
    __syncthreads();
    pref |= ((u64)s_sel) << (by*8);
    rem -= s_cum;
    __syncthreads();
  }
  for (int i = tid; i < n; i += 256){
    u64 x = sd[i];
    if (x <= pref){
      uint32 p = atomicAdd(&s_pos, 1u);
      int v = (int)(uint32)x;
      int o = nchunk * NCAND + (int)(cgt + p);
      topidx[o] = v; invc_f[o] = invn_f[v]; invc_l[o] = invn_l[v];
    }
  }
}

// ------- fused bf16 MFMA GEMM: main (K=1024) + aux (K=32) partial LSEs ---------
// LDS swizzle (both-sides, rule #21): staging pre-swizzles the GLOBAL source
// slot (LDS dest linear for global_load_lds); fragment reads XOR the slot by
// row & (LPR-1). 4-way read conflict -> 2-way (free).
__global__ void __launch_bounds__(256)
gemm_fused(const u16* __restrict__ h16, const u16* __restrict__ emb16,
           const int* __restrict__ topidx,
           const float* __restrict__ invh_f, const float* __restrict__ invc_f,
           const float* __restrict__ invh_l, const float* __restrict__ invc_l,
           const int* __restrict__ tgts, const float* __restrict__ lsc,
           float* __restrict__ pm, float* __restrict__ pa)
{
  constexpr int BK = 64, NSTEP = D_DIM / BK, KK = BK / 32;
  const int ntile = blockIdx.x, nchunk = blockIdx.y;
  const int tid = threadIdx.x, lane = tid & 63, wid = tid >> 6;
  const int wm = wid >> 1, wn = wid & 1;
  const int fq = lane >> 4, fr = lane & 15;

  __shared__ u16 As[CCHUNK * BK];
  __shared__ u16 Bs[CCHUNK * BK];
  __shared__ float s_invh[CCHUNK], s_invc[CCHUNK];
  __shared__ float s_invhl[CCHUNK], s_invcl[CCHUNK];
  __shared__ int   s_tgt[CCHUNK], s_idx[CCHUNK];

  if (tid < CCHUNK){
    s_invh[tid]  = invh_f[nchunk * CCHUNK + tid];
    s_invhl[tid] = invh_l[nchunk * CCHUNK + tid];
    s_tgt[tid]   = tgts[nchunk * CCHUNK + tid];
    int o = nchunk * NCAND + ntile * CCHUNK + tid;
    s_idx[tid]   = topidx[o];
    s_invc[tid]  = invc_f[o];
    s_invcl[tid] = invc_l[o];
  }

  // main staging: granule 8 rows x 8 slots of 16B; source slot pre-swizzled
  const int rl = lane >> 3;
  const int cbyte = ((lane & 7) ^ (rl & 7)) * 16;
  const char* aptr[4];
  const char* bptr[4];
  #pragma unroll
  for (int s = 0; s < 4; ++s){
    int row = wid * 32 + s * 8 + rl;
    aptr[s] = (const char*)h16 + ((size_t)(nchunk * CCHUNK + row)) * (D_DIM * 2) + cbyte;
    int cidx = topidx[nchunk * NCAND + ntile * CCHUNK + row];
    bptr[s] = (const char*)emb16 + (size_t)cidx * (D_DIM * 2) + cbyte;
  }

  f32x4 acc[4][4];
  #pragma unroll
  for (int m=0;m<4;++m)
    #pragma unroll
    for (int q=0;q<4;++q)
      acc[m][q] = (f32x4){0.f,0.f,0.f,0.f};

  for (int st = 0; st < NSTEP; ++st){
    const int koff = st * BK * 2;
    #pragma unroll
    for (int s = 0; s < 4; ++s){
      gload_lds16(aptr[s] + koff, (void*)&As[(wid*32 + s*8) * BK]);
      gload_lds16(bptr[s] + koff, (void*)&Bs[(wid*32 + s*8) * BK]);
    }
    __syncthreads();
    #pragma unroll
    for (int kk = 0; kk < KK; ++kk){
      short8 af[4], bf[4];
      #pragma unroll
      for (int m=0;m<4;++m){
        const int r = wm*64 + m*16 + fr, slot = kk*4 + fq;
        af[m] = *(const short8*)&As[r*BK + ((slot ^ (r & 7)) << 3)];
      }
      #pragma unroll
      for (int q=0;q<4;++q){
        const int r = wn*64 + q*16 + fr, slot = kk*4 + fq;
        bf[q] = *(const short8*)&Bs[r*BK + ((slot ^ (r & 7)) << 3)];
      }
      #pragma unroll
      for (int m=0;m<4;++m)
        #pragma unroll
        for (int q=0;q<4;++q)
          acc[m][q] = __builtin_amdgcn_mfma_f32_16x16x32_bf16(af[m], bf[q], acc[m][q], 0, 0, 0);
    }
    __syncthreads();
  }

  // ---- issue aux staging NOW (first 32 cols), latency hidden by main epilogue.
  // granule 16 rows x 4 slots of 16B; reuse As/Bs as [128][32].
  {
    const int rla = lane >> 2;
    const int cba = ((lane & 3) ^ (rla & 3)) * 16;
    #pragma unroll
    for (int s = 0; s < 2; ++s){
      int row = wid * 32 + s * 16 + rla;
      const char* ap = (const char*)h16 + ((size_t)(nchunk * CCHUNK + row)) * (D_DIM * 2) + cba;
      int cidx = topidx[nchunk * NCAND + ntile * CCHUNK + row];
      const char* bp = (const char*)emb16 + (size_t)cidx * (D_DIM * 2) + cba;
      gload_lds16(ap, (void*)&As[(wid*32 + s*16) * 32]);
      gload_lds16(bp, (void*)&Bs[(wid*32 + s*16) * 32]);
    }
  }

  const float scale = sigscale(lsc);
  const float NEG = -__builtin_huge_valf();

  // ---- main epilogue: masked per-(row, 64-col) partial (max, sumexp) -> pm ----
  #pragma unroll
  for (int m=0;m<4;++m){
    #pragma unroll
    for (int j=0;j<4;++j){
      const int c = wm*64 + m*16 + fq*4 + j;
      const float ihs = s_invh[c] * scale;
      const int tg = s_tgt[c];
      float vals[4];
      #pragma unroll
      for (int q=0;q<4;++q){
        const int kl = wn*64 + q*16 + fr;
        float lg = acc[m][q][j] * ihs * s_invc[kl];
        vals[q] = (s_idx[kl] == tg) ? NEG : lg;
      }
      float lmax = fmaxf(fmaxf(vals[0], vals[1]), fmaxf(vals[2], vals[3]));
      #pragma unroll
      for (int ms=1; ms<16; ms<<=1) lmax = fmaxf(lmax, __shfl_xor(lmax, ms, 64));
      float se = 0.f;
      #pragma unroll
      for (int q=0;q<4;++q) se += __expf(vals[q] - lmax);
      #pragma unroll
      for (int ms=1; ms<16; ms<<=1) se += __shfl_xor(se, ms, 64);
      if (fr == 0){
        size_t pos = ((size_t)((nchunk*NTILES + ntile)*2 + wn) * CCHUNK + c) * 2;
        pm[pos]   = lmax;
        pm[pos+1] = se;
      }
    }
  }

  __syncthreads();   // aux staging complete (implicit vmcnt drain) + pm reads done

  // ---- aux compute: one 16x16x32 MFMA per fragment pair -----------------------
  f32x4 acc2[4][4];
  {
    short8 afa[4], bfa[4];
    #pragma unroll
    for (int m=0;m<4;++m){
      const int r = wm*64 + m*16 + fr;
      afa[m] = *(const short8*)&As[r*32 + ((fq ^ (r & 3)) << 3)];
    }
    #pragma unroll
    for (int q=0;q<4;++q){
      const int r = wn*64 + q*16 + fr;
      bfa[q] = *(const short8*)&Bs[r*32 + ((fq ^ (r & 3)) << 3)];
    }
    #pragma unroll
    for (int m=0;m<4;++m)
      #pragma unroll
      for (int q=0;q<4;++q)
        acc2[m][q] = __builtin_amdgcn_mfma_f32_16x16x32_bf16(
            afa[m], bfa[q], (f32x4){0.f,0.f,0.f,0.f}, 0, 0, 0);
  }

  // ---- aux epilogue -> pa -----------------------------------------------------
  #pragma unroll
  for (int m=0;m<4;++m){
    #pragma unroll
    for (int j=0;j<4;++j){
      const int c = wm*64 + m*16 + fq*4 + j;
      const float ihs = s_invhl[c] * scale;
      const int tg = s_tgt[c];
      float vals[4];
      #pragma unroll
      for (int q=0;q<4;++q){
        const int kl = wn*64 + q*16 + fr;
        float lg = acc2[m][q][j] * ihs * s_invcl[kl];
        vals[q] = (s_idx[kl] == tg) ? NEG : lg;
      }
      float lmax = fmaxf(fmaxf(vals[0], vals[1]), fmaxf(vals[2], vals[3]));
      #pragma unroll
      for (int ms=1; ms<16; ms<<=1) lmax = fmaxf(lmax, __shfl_xor(lmax, ms, 64));
      float se = 0.f;
      #pragma unroll
      for (int q=0;q<4;++q) se += __expf(vals[q] - lmax);
      #pragma unroll
      for (int ms=1; ms<16; ms<<=1) se += __shfl_xor(se, ms, 64);
      if (fr == 0){
        size_t pos = ((size_t)((nchunk*NTILES + ntile)*2 + wn) * CCHUNK + c) * 2;
        pa[pos]   = lmax;
        pa[pos+1] = se;
      }
    }
  }
}

// ---------------- merge partials + target term -> scalar loss ------------------
__global__ void __launch_bounds__(256)
merge_loss(const u16* __restrict__ h16, const u16* __restrict__ emb16,
           const int* __restrict__ tgts,
           const float* __restrict__ invh_f, const float* __restrict__ invh_l,
           const float* __restrict__ invn_f, const float* __restrict__ invn_l,
           const float* __restrict__ pm, const float* __restrict__ pa,
           const float* __restrict__ lsc, float* __restrict__ out)
{
  const int nchunk = blockIdx.x >> 2, quarter = blockIdx.x & 3;
  const int tid = threadIdx.x, lane = tid & 63, wid = tid >> 6;
  const float scale = sigscale(lsc);
  const float NEG = -__builtin_huge_valf();
  float wacc = 0.f;
  for (int i = 0; i < 8; ++i){
    const int loc = quarter*32 + wid*8 + i;
    const int tok = nchunk * CCHUNK + loc;
    const int t = tgts[tok];
    float part = 0.f;
    {
      const uint4* hp = (const uint4*)(h16 + (size_t)tok * D_DIM) + lane*2;
      const uint4* ep = (const uint4*)(emb16 + (size_t)t * D_DIM) + lane*2;
      uint4 hx = hp[0], hy = hp[1], ex = ep[0], ey = ep[1];
      uint32 hu[8] = {hx.x,hx.y,hx.z,hx.w,hy.x,hy.y,hy.z,hy.w};
      uint32 eu[8] = {ex.x,ex.y,ex.z,ex.w,ey.x,ey.y,ey.z,ey.w};
      #pragma unroll
      for (int k=0;k<8;++k){
        float h0 = __uint_as_float(hu[k] << 16);
        float h1 = __uint_as_float(hu[k] & 0xFFFF0000u);
        float e0 = __uint_as_float(eu[k] << 16);
        float e1 = __uint_as_float(eu[k] & 0xFFFF0000u);
        part += h0*e0 + h1*e1;
      }
    }
    float dfull = wred_sum(part);
    float dlow  = wred_sum(lane < 2 ? part : 0.f);
    float tful = dfull * invh_f[tok] * invn_f[t] * scale;
    float tlow = dlow  * invh_l[tok] * invn_l[t] * scale;

    float mi = NEG, si = 0.f, mia = NEG, sia = 0.f;
    if (lane < 32){
      size_t q = ((size_t)(nchunk*32 + lane) * CCHUNK + loc) * 2;
      mi  = pm[q]; si  = pm[q+1];
      mia = pa[q]; sia = pa[q+1];
    }
    float M  = wred_max(mi);
    float S  = wred_sum(lane < 32 ? si * __expf(mi - M) : 0.f);
    float M2 = fmaxf(M, tful);
    float lmain = __logf(S * __expf(M - M2) + __expf(tful - M2)) + M2 - tful;
    float Ma  = wred_max(mia);
    float Sa  = wred_sum(lane < 32 ? sia * __expf(mia - Ma) : 0.f);
    float M2a = fmaxf(Ma, tlow);
    float laux = __logf(Sa * __expf(Ma - M2a) + __expf(tlow - M2a)) + M2a - tlow;
    wacc += lmain + 0.2f * laux;
  }
  __shared__ float ws4[4];
  if (lane == 0) ws4[wid] = wacc;
  __syncthreads();
  if (tid == 0) atomicAdd(out, (ws4[0]+ws4[1]+ws4[2]+ws4[3]) * (1.f / (float)T_TOK));
}

// ---------------- host ---------------------------------------------------------
extern "C" void kernel_launch(void* const* d_in, const int* in_sizes, int n_in,
                              void* d_out, int out_size, void* d_ws, size_t ws_size,
                              hipStream_t stream)
{
  (void)in_sizes; (void)n_in; (void)out_size; (void)ws_size;
  const float* h   = (const float*)d_in[0];
  const float* emb = (const float*)d_in[1];
  const float* lsc = (const float*)d_in[2];
  const int*   tgt = (const int*)d_in[3];
  float* out = (float*)d_out;

  uint8_t* p = (uint8_t*)d_ws;
  auto carve = [&](size_t n)->uint8_t*{
    uint8_t* r = p; p += (n + 255) & ~(size_t)255; return r;
  };
  u16*   emb16  = (u16*)  carve((size_t)V_SIZE * D_DIM * 2);
  float* invn_f = (float*)carve((size_t)V_SIZE * 4);
  float* invn_l = (float*)carve((size_t)V_SIZE * 4);
  u16*   h16    = (u16*)  carve((size_t)T_TOK * D_DIM * 2);
  float* invh_f = (float*)carve((size_t)T_TOK * 4);
  float* invh_l = (float*)carve((size_t)T_TOK * 4);
  float* hpart  = (float*)carve((size_t)NCHUNK * 8 * LOWR * 4);
  float* scan   = (float*)carve((size_t)NCHUNK * V_PAD * 4);
  int*   topidx = (int*)  carve((size_t)NCHUNK * NCAND * 4);
  float* invc_f = (float*)carve((size_t)NCHUNK * NCAND * 4);
  float* invc_l = (float*)carve((size_t)NCHUNK * NCAND * 4);
  float* pm     = (float*)carve((size_t)NCHUNK * 32 * CCHUNK * 2 * 4);
  float* pa     = (float*)carve((size_t)NCHUNK * 32 * CCHUNK * 2 * 4);
  uint32* cnt_gt  = (uint32*)carve((size_t)NCHUNK * 32 * 4);
  uint32* cnt_bin = (uint32*)carve((size_t)NCHUNK * 32 * 4);
  uint32* thr  = (uint32*)carve((size_t)NCHUNK * 2 * 4);
  u64*    side = (u64*)  carve((size_t)NCHUNK * SIDE_PER * 8);

  token_prep<<<dim3(NCHUNK, 8), dim3(256), 0, stream>>>(h, h16, invh_f, invh_l, hpart, out);
  vocab_prep<<<dim3((V_SIZE + 3) / 4), dim3(256), 0, stream>>>(emb, emb16, invn_f, invn_l);
  scan_kernel<<<dim3(V_PAD / 256), dim3(256), 0, stream>>>(emb, invn_l, hpart, scan);
  topk_prepass<<<dim3(NCHUNK), dim3(1024), 0, stream>>>(scan, thr, cnt_gt, cnt_bin);
  topk_collect<<<dim3(NCHUNK, 8), dim3(256), 0, stream>>>(
      scan, thr, cnt_gt, cnt_bin, side, topidx, invc_f, invc_l, invn_f, invn_l);
  topk_refine<<<dim3(NCHUNK), dim3(256), 0, stream>>>(
      thr, cnt_bin, side, topidx, invc_f, invc_l, invn_f, invn_l);
  gemm_fused<<<dim3(NTILES, NCHUNK), dim3(256), 0, stream>>>(
      h16, emb16, topidx, invh_f, invc_f, invh_l, invc_l, tgt, lsc, pm, pa);
  merge_loss<<<dim3(NCHUNK * 4), dim3(256), 0, stream>>>(
      h16, emb16, tgt, invh_f, invh_l, invn_f, invn_l, pm, pa, lsc, out);
}

// Round 5
// 255.205 us; speedup vs baseline: 2.0242x; 1.0413x over previous
//
#include <hip/hip_runtime.h>
#include <cstdint>
#include <cstddef>

#define V_SIZE 50257
#define V_PAD  50432
#define NV4    (V_PAD/4)
#define NVB    ((V_SIZE + 3) / 4)
#define D_DIM  1024
#define T_TOK  8192
#define NCHUNK 64
#define CCHUNK 128
#define NCAND  2048
#define NTILES 16
#define LOWR   32

typedef unsigned int  uint32;
typedef unsigned short u16;
typedef unsigned long long u64;
typedef __attribute__((ext_vector_type(8))) short short8;
typedef __attribute__((ext_vector_type(4))) float f32x4;

__device__ __forceinline__ u16 f2bf(float f){
  uint32 u = __float_as_uint(f);
  return (u16)((u + 0x7FFFu + ((u >> 16) & 1u)) >> 16);
}
__device__ __forceinline__ uint32 key_of(float f){
  uint32 b = __float_as_uint(f);
  return b ^ ((uint32)((int)b >> 31) | 0x80000000u);
}
__device__ __forceinline__ float sigscale(const float* lsc){
  return 100.f / (1.f + __expf(-lsc[0])) + 1.f;
}
__device__ __forceinline__ float wred_sum(float v){
  #pragma unroll
  for (int m = 32; m >= 1; m >>= 1) v += __shfl_xor(v, m, 64);
  return v;
}
__device__ __forceinline__ float wred_max(float v){
  #pragma unroll
  for (int m = 32; m >= 1; m >>= 1) v = fmaxf(v, __shfl_xor(v, m, 64));
  return v;
}
__device__ __forceinline__ void gload_lds16(const void* g, void* l){
  __builtin_amdgcn_global_load_lds(
      (const __attribute__((address_space(1))) uint32*)g,
      (__attribute__((address_space(3))) uint32*)l, 16, 0, 0);
}
__device__ __forceinline__ void load_row16(const float* base, int lane, float* f){
  const float4* s4 = (const float4*)(base + lane * 16);
  float4 t0 = s4[0], t1 = s4[1], t2 = s4[2], t3 = s4[3];
  f[0]=t0.x; f[1]=t0.y; f[2]=t0.z;  f[3]=t0.w;
  f[4]=t1.x; f[5]=t1.y; f[6]=t1.z;  f[7]=t1.w;
  f[8]=t2.x; f[9]=t2.y; f[10]=t2.z; f[11]=t2.w;
  f[12]=t3.x; f[13]=t3.y; f[14]=t3.z; f[15]=t3.w;
}
__device__ __forceinline__ void store_bf16x16(u16* dst_base, int lane, const float* f){
  uint32 pk[8];
  #pragma unroll
  for (int i=0;i<8;++i) pk[i] = (uint32)f2bf(f[2*i]) | ((uint32)f2bf(f[2*i+1]) << 16);
  uint4* d = (uint4*)(dst_base + lane * 16);
  d[0] = make_uint4(pk[0],pk[1],pk[2],pk[3]);
  d[1] = make_uint4(pk[4],pk[5],pk[6],pk[7]);
}

// ------- fused prep: vocab (blocks [0,NVB)) + tokens (blocks [NVB,NVB+512)) ----
__global__ void __launch_bounds__(256)
prep_kernel(const float* __restrict__ emb, u16* __restrict__ emb16,
            float* __restrict__ invn_f, float* __restrict__ invn_l,
            const float* __restrict__ h, u16* __restrict__ h16,
            float* __restrict__ invh_f, float* __restrict__ invh_l,
            float* __restrict__ hpart, float* __restrict__ out)
{
  const int bid = blockIdx.x;
  const int tid = threadIdx.x, lane = tid & 63, wid = tid >> 6;
  if (bid < NVB){
    if (bid == 0 && tid == 0) out[0] = 0.f;   // zero loss accumulator
    const int v = bid * 4 + wid;
    if (v >= V_SIZE) return;
    float f[16];
    load_row16(emb + (size_t)v * D_DIM, lane, f);
    float ss = 0.f;
    #pragma unroll
    for (int k=0;k<16;++k) ss += f[k]*f[k];
    float fullss = wred_sum(ss);
    float lowss  = wred_sum(lane < 2 ? ss : 0.f);   // lanes 0,1 own elems 0..31
    store_bf16x16(emb16 + (size_t)v * D_DIM, lane, f);
    if (lane == 0){
      invn_f[v] = 1.f / fmaxf(sqrtf(fullss), 1e-12f);
      invn_l[v] = 1.f / fmaxf(sqrtf(lowss),  1e-12f);
    }
    return;
  }
  // token path
  const int bid2 = bid - NVB;
  const int nchunk = bid2 >> 3, sub = bid2 & 7;
  __shared__ float hm[LOWR];
  if (tid < LOWR) hm[tid] = 0.f;
  __syncthreads();
  for (int i = 0; i < 4; ++i){
    const int loc = sub*16 + wid*4 + i;
    const int tok = nchunk * CCHUNK + loc;
    float f[16];
    load_row16(h + (size_t)tok * D_DIM, lane, f);
    float ss = 0.f;
    #pragma unroll
    for (int k=0;k<16;++k) ss += f[k]*f[k];
    float fullss = wred_sum(ss);
    float lowss  = wred_sum(lane < 2 ? ss : 0.f);
    float invf = 1.f / fmaxf(sqrtf(fullss), 1e-12f);
    float invl = 1.f / fmaxf(sqrtf(lowss),  1e-12f);
    store_bf16x16(h16 + (size_t)tok * D_DIM, lane, f);
    if (lane == 0){ invh_f[tok] = invf; invh_l[tok] = invl; }
    if (lane < 2){
      #pragma unroll
      for (int k=0;k<16;++k) atomicAdd(&hm[lane*16 + k], f[k] * invl * (1.f/128.f));
    }
  }
  __syncthreads();
  if (tid < LOWR) hpart[(size_t)(nchunk*8 + sub) * LOWR + tid] = hm[tid];
}

// ---------------- scan: scan_logits[n][v] = h_mean[n] . normalize(emb[v,:32]) --
__global__ void __launch_bounds__(256)
scan_kernel(const float* __restrict__ emb, const float* __restrict__ invn_l,
            const float* __restrict__ hpart, float* __restrict__ scan)
{
  __shared__ float hm[NCHUNK * LOWR];
  for (int i = threadIdx.x; i < NCHUNK * LOWR; i += 256){
    const int nn = i >> 5, l = i & 31;
    float s = 0.f;
    #pragma unroll
    for (int p = 0; p < 8; ++p) s += hpart[(size_t)(nn*8 + p) * LOWR + l];
    hm[i] = s;
  }
  __syncthreads();
  const int v = blockIdx.x * 256 + threadIdx.x;
  if (v >= V_SIZE){
    if (v < V_PAD)
      for (int nn = 0; nn < NCHUNK; ++nn) scan[(size_t)nn * V_PAD + v] = -3.4e38f;
    return;
  }
  float w[LOWR];
  const float4* s4 = (const float4*)(emb + (size_t)v * D_DIM);
  #pragma unroll
  for (int i=0;i<8;++i){
    float4 t = s4[i];
    w[4*i]=t.x; w[4*i+1]=t.y; w[4*i+2]=t.z; w[4*i+3]=t.w;
  }
  const float inv = invn_l[v];
  #pragma unroll
  for (int i=0;i<LOWR;++i) w[i] *= inv;
  for (int nn = 0; nn < NCHUNK; ++nn){
    float d = 0.f;
    #pragma unroll
    for (int l=0;l<LOWR;++l) d += w[l] * hm[nn*LOWR + l];
    scan[(size_t)nn * V_PAD + v] = d;
  }
}

// ---- single-kernel exact top-K per chunk: hist + threshold + compact + refine -
__global__ void __launch_bounds__(1024)
topk_all(const float* __restrict__ scan,
         const float* __restrict__ invn_f, const float* __restrict__ invn_l,
         int* __restrict__ topidx, float* __restrict__ invc_f, float* __restrict__ invc_l)
{
  const int nchunk = blockIdx.x, tid = threadIdx.x;
  __shared__ uint32 h[4096];          // 16 KB (reused: 256 bins in refine)
  __shared__ int gt_list[2048];       //  8 KB (cgt < NCAND guaranteed)
  __shared__ u64 sd_list[4096];       // 32 KB (threshold-bin entries, capped)
  __shared__ uint32 n_gt, n_sd, s_tb, s_cgt, s_sel, s_cum, s_pos;
  if (tid == 0){ n_gt = 0; n_sd = 0; s_pos = 0; }
  for (int i = tid; i < 4096; i += 1024) h[i] = 0;
  __syncthreads();
  const float4* row = (const float4*)(scan + (size_t)nchunk * V_PAD);
  // pass 1: 12-bit histogram
  for (int i = tid; i < NV4; i += 1024){
    float4 x = row[i];
    atomicAdd(&h[key_of(x.x) >> 20], 1u);
    atomicAdd(&h[key_of(x.y) >> 20], 1u);
    atomicAdd(&h[key_of(x.z) >> 20], 1u);
    atomicAdd(&h[key_of(x.w) >> 20], 1u);
  }
  __syncthreads();
  // threshold: wave 0 does coarse(64x64) + fine suffix scans
  if (tid < 64){
    const int lane = tid;
    uint32 c = 0;
    #pragma unroll 8
    for (int k = 0; k < 64; ++k) c += h[lane*64 + k];
    uint32 s = c;
    #pragma unroll
    for (int off = 1; off < 64; off <<= 1){
      uint32 t = __shfl_down(s, off, 64);
      if (lane + off < 64) s += t;
    }
    u64 m1 = __ballot(s >= NCAND);
    const int g = 63 - __builtin_clzll(m1);
    const uint32 cum = (g < 63) ? __shfl(s, g + 1, 64) : 0u;
    uint32 s2 = h[g*64 + lane];
    #pragma unroll
    for (int off = 1; off < 64; off <<= 1){
      uint32 t = __shfl_down(s2, off, 64);
      if (lane + off < 64) s2 += t;
    }
    u64 m2 = __ballot(cum + s2 >= NCAND);
    const int j = 63 - __builtin_clzll(m2);
    const uint32 cgt = cum + ((j < 63) ? __shfl(s2, j + 1, 64) : 0u);
    if (lane == 0){ s_tb = (uint32)(g*64 + j); s_cgt = cgt; }
  }
  __syncthreads();
  const uint32 tb = s_tb, cgt = s_cgt;
  // pass 2: classify into LDS lists
  for (int i = tid; i < NV4; i += 1024){
    float4 x = row[i];
    const int vbase = i * 4;
    float vals[4] = {x.x, x.y, x.z, x.w};
    #pragma unroll
    for (int c = 0; c < 4; ++c){
      uint32 u = key_of(vals[c]);
      uint32 b = u >> 20;
      const int v = vbase + c;
      if (b < tb || v >= V_SIZE) continue;
      if (b > tb){
        uint32 p = atomicAdd(&n_gt, 1u);
        if (p < 2048u) gt_list[p] = v;
      } else {
        uint32 p = atomicAdd(&n_sd, 1u);
        if (p < 4096u) sd_list[p] = ((u64)(~u) << 32) | (uint32)v;
      }
    }
  }
  __syncthreads();
  // write strictly-greater candidates
  const uint32 ng = n_gt < 2048u ? n_gt : 2048u;
  for (uint32 i = tid; i < ng; i += 1024){
    const int v = gt_list[i];
    const int o = nchunk * NCAND + (int)i;
    topidx[o] = v; invc_f[o] = invn_f[v]; invc_l[o] = invn_l[v];
  }
  // refine: r-th smallest u64 over threshold-bin entries (all distinct)
  const int n = (int)(n_sd < 4096u ? n_sd : 4096u);
  uint32 r = NCAND - cgt; if ((int)r > n) r = (uint32)n;
  u64 pref = 0; uint32 rem = r;
  for (int by = 7; by >= 0; --by){
    if (tid < 256) h[tid] = 0;
    __syncthreads();
    const u64 pmask = (by == 7) ? 0ull : (~0ull << ((by+1)*8));
    for (int i = tid; i < n; i += 1024){
      u64 x = sd_list[i];
      if ((x & pmask) == pref) atomicAdd(&h[(uint32)(x >> (by*8)) & 255u], 1u);
    }
    __syncthreads();
    if (tid == 0){
      uint32 cum = 0; int b = 0;
      for (; b < 255; ++b){ if (cum + h[b] >= rem) break; cum += h[b]; }
      s_sel = (uint32)b; s_cum = cum;
    }
    __syncthreads();
    pref |= ((u64)s_sel) << (by*8);
    rem -= s_cum;
    __syncthreads();
  }
  for (int i = tid; i < n; i += 1024){
    u64 x = sd_list[i];
    if (x <= pref){
      uint32 p = atomicAdd(&s_pos, 1u);
      const int v = (int)(uint32)x;
      const int o = nchunk * NCAND + (int)(cgt + p);
      topidx[o] = v; invc_f[o] = invn_f[v]; invc_l[o] = invn_l[v];
    }
  }
}

// ------- fused bf16 MFMA GEMM: main (K=1024) + aux (K=32) partial LSEs ---------
// XCD swizzle: id = (chunk&7) + 8*(tile + 16*(chunk>>3)) keeps a chunk's 16
// tiles on one XCD (A-tile + B-gather L2 reuse). LDS swizzle both-sides (#21).
__global__ void __launch_bounds__(256)
gemm_fused(const u16* __restrict__ h16, const u16* __restrict__ emb16,
           const int* __restrict__ topidx,
           const float* __restrict__ invh_f, const float* __restrict__ invc_f,
           const float* __restrict__ invh_l, const float* __restrict__ invc_l,
           const int* __restrict__ tgts, const float* __restrict__ lsc,
           float* __restrict__ pm, float* __restrict__ pa)
{
  constexpr int BK = 64, NSTEP = D_DIM / BK, KK = BK / 32;
  const int id = blockIdx.x;
  const int s_ = id >> 3;
  const int ntile = s_ & 15;
  const int nchunk = ((s_ >> 4) << 3) | (id & 7);
  const int tid = threadIdx.x, lane = tid & 63, wid = tid >> 6;
  const int wm = wid >> 1, wn = wid & 1;
  const int fq = lane >> 4, fr = lane & 15;

  __shared__ u16 As[CCHUNK * BK];
  __shared__ u16 Bs[CCHUNK * BK];
  __shared__ float s_invh[CCHUNK], s_invc[CCHUNK];
  __shared__ float s_invhl[CCHUNK], s_invcl[CCHUNK];
  __shared__ int   s_tgt[CCHUNK], s_idx[CCHUNK];

  if (tid < CCHUNK){
    s_invh[tid]  = invh_f[nchunk * CCHUNK + tid];
    s_invhl[tid] = invh_l[nchunk * CCHUNK + tid];
    s_tgt[tid]   = tgts[nchunk * CCHUNK + tid];
    int o = nchunk * NCAND + ntile * CCHUNK + tid;
    s_idx[tid]   = topidx[o];
    s_invc[tid]  = invc_f[o];
    s_invcl[tid] = invc_l[o];
  }

  // main staging: granule 8 rows x 8 slots of 16B; source slot pre-swizzled
  const int rl = lane >> 3;
  const int cbyte = ((lane & 7) ^ (rl & 7)) * 16;
  const char* aptr[4];
  const char* bptr[4];
  #pragma unroll
  for (int s = 0; s < 4; ++s){
    int row = wid * 32 + s * 8 + rl;
    aptr[s] = (const char*)h16 + ((size_t)(nchunk * CCHUNK + row)) * (D_DIM * 2) + cbyte;
    int cidx = topidx[nchunk * NCAND + ntile * CCHUNK + row];
    bptr[s] = (const char*)emb16 + (size_t)cidx * (D_DIM * 2) + cbyte;
  }

  f32x4 acc[4][4];
  #pragma unroll
  for (int m=0;m<4;++m)
    #pragma unroll
    for (int q=0;q<4;++q)
      acc[m][q] = (f32x4){0.f,0.f,0.f,0.f};

  for (int st = 0; st < NSTEP; ++st){
    const int koff = st * BK * 2;
    #pragma unroll
    for (int s = 0; s < 4; ++s){
      gload_lds16(aptr[s] + koff, (void*)&As[(wid*32 + s*8) * BK]);
      gload_lds16(bptr[s] + koff, (void*)&Bs[(wid*32 + s*8) * BK]);
    }
    __syncthreads();
    #pragma unroll
    for (int kk = 0; kk < KK; ++kk){
      short8 af[4], bf[4];
      #pragma unroll
      for (int m=0;m<4;++m){
        const int r = wm*64 + m*16 + fr, slot = kk*4 + fq;
        af[m] = *(const short8*)&As[r*BK + ((slot ^ (r & 7)) << 3)];
      }
      #pragma unroll
      for (int q=0;q<4;++q){
        const int r = wn*64 + q*16 + fr, slot = kk*4 + fq;
        bf[q] = *(const short8*)&Bs[r*BK + ((slot ^ (r & 7)) << 3)];
      }
      #pragma unroll
      for (int m=0;m<4;++m)
        #pragma unroll
        for (int q=0;q<4;++q)
          acc[m][q] = __builtin_amdgcn_mfma_f32_16x16x32_bf16(af[m], bf[q], acc[m][q], 0, 0, 0);
    }
    __syncthreads();
  }

  // issue aux staging now (first 32 cols); latency hidden by main epilogue
  {
    const int rla = lane >> 2;
    const int cba = ((lane & 3) ^ (rla & 3)) * 16;
    #pragma unroll
    for (int s = 0; s < 2; ++s){
      int row = wid * 32 + s * 16 + rla;
      const char* ap = (const char*)h16 + ((size_t)(nchunk * CCHUNK + row)) * (D_DIM * 2) + cba;
      int cidx = topidx[nchunk * NCAND + ntile * CCHUNK + row];
      const char* bp = (const char*)emb16 + (size_t)cidx * (D_DIM * 2) + cba;
      gload_lds16(ap, (void*)&As[(wid*32 + s*16) * 32]);
      gload_lds16(bp, (void*)&Bs[(wid*32 + s*16) * 32]);
    }
  }

  const float scale = sigscale(lsc);
  const float NEG = -__builtin_huge_valf();

  // main epilogue -> pm
  #pragma unroll
  for (int m=0;m<4;++m){
    #pragma unroll
    for (int j=0;j<4;++j){
      const int c = wm*64 + m*16 + fq*4 + j;
      const float ihs = s_invh[c] * scale;
      const int tg = s_tgt[c];
      float vals[4];
      #pragma unroll
      for (int q=0;q<4;++q){
        const int kl = wn*64 + q*16 + fr;
        float lg = acc[m][q][j] * ihs * s_invc[kl];
        vals[q] = (s_idx[kl] == tg) ? NEG : lg;
      }
      float lmax = fmaxf(fmaxf(vals[0], vals[1]), fmaxf(vals[2], vals[3]));
      #pragma unroll
      for (int ms=1; ms<16; ms<<=1) lmax = fmaxf(lmax, __shfl_xor(lmax, ms, 64));
      float se = 0.f;
      #pragma unroll
      for (int q=0;q<4;++q) se += __expf(vals[q] - lmax);
      #pragma unroll
      for (int ms=1; ms<16; ms<<=1) se += __shfl_xor(se, ms, 64);
      if (fr == 0){
        size_t pos = ((size_t)((nchunk*NTILES + ntile)*2 + wn) * CCHUNK + c) * 2;
        pm[pos]   = lmax;
        pm[pos+1] = se;
      }
    }
  }

  __syncthreads();   // aux staging drained + main LDS reads done

  // aux compute: one MFMA per fragment pair
  f32x4 acc2[4][4];
  {
    short8 afa[4], bfa[4];
    #pragma unroll
    for (int m=0;m<4;++m){
      const int r = wm*64 + m*16 + fr;
      afa[m] = *(const short8*)&As[r*32 + ((fq ^ (r & 3)) << 3)];
    }
    #pragma unroll
    for (int q=0;q<4;++q){
      const int r = wn*64 + q*16 + fr;
      bfa[q] = *(const short8*)&Bs[r*32 + ((fq ^ (r & 3)) << 3)];
    }
    #pragma unroll
    for (int m=0;m<4;++m)
      #pragma unroll
      for (int q=0;q<4;++q)
        acc2[m][q] = __builtin_amdgcn_mfma_f32_16x16x32_bf16(
            afa[m], bfa[q], (f32x4){0.f,0.f,0.f,0.f}, 0, 0, 0);
  }

  // aux epilogue -> pa
  #pragma unroll
  for (int m=0;m<4;++m){
    #pragma unroll
    for (int j=0;j<4;++j){
      const int c = wm*64 + m*16 + fq*4 + j;
      const float ihs = s_invhl[c] * scale;
      const int tg = s_tgt[c];
      float vals[4];
      #pragma unroll
      for (int q=0;q<4;++q){
        const int kl = wn*64 + q*16 + fr;
        float lg = acc2[m][q][j] * ihs * s_invcl[kl];
        vals[q] = (s_idx[kl] == tg) ? NEG : lg;
      }
      float lmax = fmaxf(fmaxf(vals[0], vals[1]), fmaxf(vals[2], vals[3]));
      #pragma unroll
      for (int ms=1; ms<16; ms<<=1) lmax = fmaxf(lmax, __shfl_xor(lmax, ms, 64));
      float se = 0.f;
      #pragma unroll
      for (int q=0;q<4;++q) se += __expf(vals[q] - lmax);
      #pragma unroll
      for (int ms=1; ms<16; ms<<=1) se += __shfl_xor(se, ms, 64);
      if (fr == 0){
        size_t pos = ((size_t)((nchunk*NTILES + ntile)*2 + wn) * CCHUNK + c) * 2;
        pa[pos]   = lmax;
        pa[pos+1] = se;
      }
    }
  }
}

// ---------------- merge partials + target term -> scalar loss ------------------
__global__ void __launch_bounds__(256)
merge_loss(const u16* __restrict__ h16, const u16* __restrict__ emb16,
           const int* __restrict__ tgts,
           const float* __restrict__ invh_f, const float* __restrict__ invh_l,
           const float* __restrict__ invn_f, const float* __restrict__ invn_l,
           const float* __restrict__ pm, const float* __restrict__ pa,
           const float* __restrict__ lsc, float* __restrict__ out)
{
  const int nchunk = blockIdx.x >> 2, quarter = blockIdx.x & 3;
  const int tid = threadIdx.x, lane = tid & 63, wid = tid >> 6;
  const float scale = sigscale(lsc);
  const float NEG = -__builtin_huge_valf();
  float wacc = 0.f;
  for (int i = 0; i < 8; ++i){
    const int loc = quarter*32 + wid*8 + i;
    const int tok = nchunk * CCHUNK + loc;
    const int t = tgts[tok];
    float part = 0.f;
    {
      const uint4* hp = (const uint4*)(h16 + (size_t)tok * D_DIM) + lane*2;
      const uint4* ep = (const uint4*)(emb16 + (size_t)t * D_DIM) + lane*2;
      uint4 hx = hp[0], hy = hp[1], ex = ep[0], ey = ep[1];
      uint32 hu[8] = {hx.x,hx.y,hx.z,hx.w,hy.x,hy.y,hy.z,hy.w};
      uint32 eu[8] = {ex.x,ex.y,ex.z,ex.w,ey.x,ey.y,ey.z,ey.w};
      #pragma unroll
      for (int k=0;k<8;++k){
        float h0 = __uint_as_float(hu[k] << 16);
        float h1 = __uint_as_float(hu[k] & 0xFFFF0000u);
        float e0 = __uint_as_float(eu[k] << 16);
        float e1 = __uint_as_float(eu[k] & 0xFFFF0000u);
        part += h0*e0 + h1*e1;
      }
    }
    float dfull = wred_sum(part);
    float dlow  = wred_sum(lane < 2 ? part : 0.f);
    float tful = dfull * invh_f[tok] * invn_f[t] * scale;
    float tlow = dlow  * invh_l[tok] * invn_l[t] * scale;

    float mi = NEG, si = 0.f, mia = NEG, sia = 0.f;
    if (lane < 32){
      size_t q = ((size_t)(nchunk*32 + lane) * CCHUNK + loc) * 2;
      mi  = pm[q]; si  = pm[q+1];
      mia = pa[q]; sia = pa[q+1];
    }
    float M  = wred_max(mi);
    float S  = wred_sum(lane < 32 ? si * __expf(mi - M) : 0.f);
    float M2 = fmaxf(M, tful);
    float lmain = __logf(S * __expf(M - M2) + __expf(tful - M2)) + M2 - tful;
    float Ma  = wred_max(mia);
    float Sa  = wred_sum(lane < 32 ? sia * __expf(mia - Ma) : 0.f);
    float M2a = fmaxf(Ma, tlow);
    float laux = __logf(Sa * __expf(Ma - M2a) + __expf(tlow - M2a)) + M2a - tlow;
    wacc += lmain + 0.2f * laux;
  }
  __shared__ float ws4[4];
  if (lane == 0) ws4[wid] = wacc;
  __syncthreads();
  if (tid == 0) atomicAdd(out, (ws4[0]+ws4[1]+ws4[2]+ws4[3]) * (1.f / (float)T_TOK));
}

// ---------------- host ---------------------------------------------------------
extern "C" void kernel_launch(void* const* d_in, const int* in_sizes, int n_in,
                              void* d_out, int out_size, void* d_ws, size_t ws_size,
                              hipStream_t stream)
{
  (void)in_sizes; (void)n_in; (void)out_size; (void)ws_size;
  const float* h   = (const float*)d_in[0];
  const float* emb = (const float*)d_in[1];
  const float* lsc = (const float*)d_in[2];
  const int*   tgt = (const int*)d_in[3];
  float* out = (float*)d_out;

  uint8_t* p = (uint8_t*)d_ws;
  auto carve = [&](size_t n)->uint8_t*{
    uint8_t* r = p; p += (n + 255) & ~(size_t)255; return r;
  };
  u16*   emb16  = (u16*)  carve((size_t)V_SIZE * D_DIM * 2);
  float* invn_f = (float*)carve((size_t)V_SIZE * 4);
  float* invn_l = (float*)carve((size_t)V_SIZE * 4);
  u16*   h16    = (u16*)  carve((size_t)T_TOK * D_DIM * 2);
  float* invh_f = (float*)carve((size_t)T_TOK * 4);
  float* invh_l = (float*)carve((size_t)T_TOK * 4);
  float* hpart  = (float*)carve((size_t)NCHUNK * 8 * LOWR * 4);
  float* scan   = (float*)carve((size_t)NCHUNK * V_PAD * 4);
  int*   topidx = (int*)  carve((size_t)NCHUNK * NCAND * 4);
  float* invc_f = (float*)carve((size_t)NCHUNK * NCAND * 4);
  float* invc_l = (float*)carve((size_t)NCHUNK * NCAND * 4);
  float* pm     = (float*)carve((size_t)NCHUNK * 32 * CCHUNK * 2 * 4);
  float* pa     = (float*)carve((size_t)NCHUNK * 32 * CCHUNK * 2 * 4);

  prep_kernel<<<dim3(NVB + NCHUNK*8), dim3(256), 0, stream>>>(
      emb, emb16, invn_f, invn_l, h, h16, invh_f, invh_l, hpart, out);
  scan_kernel<<<dim3(V_PAD / 256), dim3(256), 0, stream>>>(emb, invn_l, hpart, scan);
  topk_all<<<dim3(NCHUNK), dim3(1024), 0, stream>>>(
      scan, invn_f, invn_l, topidx, invc_f, invc_l);
  gemm_fused<<<dim3(NTILES * NCHUNK), dim3(256), 0, stream>>>(
      h16, emb16, topidx, invh_f, invc_f, invh_l, invc_l, tgt, lsc, pm, pa);
  merge_loss<<<dim3(NCHUNK * 4), dim3(256), 0, stream>>>(
      h16, emb16, tgt, invh_f, invh_l, invn_f, invn_l, pm, pa, lsc, out);
}

// Round 6
// 212.620 us; speedup vs baseline: 2.4297x; 1.2003x over previous
//
#include <hip/hip_runtime.h>
#include <cstdint>
#include <cstddef>

#define V_SIZE 50257
#define V_PAD  50432
#define NV4    (V_PAD/4)
#define NVB    ((V_SIZE + 3) / 4)
#define D_DIM  1024
#define T_TOK  8192
#define NCHUNK 64
#define CCHUNK 128
#define NCAND  2048
#define NTILES 16
#define LOWR   32
#define SDCAP  6144

typedef unsigned int  uint32;
typedef unsigned short u16;
typedef unsigned long long u64;
typedef __attribute__((ext_vector_type(8))) short short8;
typedef __attribute__((ext_vector_type(4))) float f32x4;

__device__ __forceinline__ u16 f2bf(float f){
  uint32 u = __float_as_uint(f);
  return (u16)((u + 0x7FFFu + ((u >> 16) & 1u)) >> 16);
}
__device__ __forceinline__ uint32 key_of(float f){
  uint32 b = __float_as_uint(f);
  return b ^ ((uint32)((int)b >> 31) | 0x80000000u);
}
__device__ __forceinline__ float sigscale(const float* lsc){
  return 100.f / (1.f + __expf(-lsc[0])) + 1.f;
}
__device__ __forceinline__ float wred_sum(float v){
  #pragma unroll
  for (int m = 32; m >= 1; m >>= 1) v += __shfl_xor(v, m, 64);
  return v;
}
__device__ __forceinline__ float wred_max(float v){
  #pragma unroll
  for (int m = 32; m >= 1; m >>= 1) v = fmaxf(v, __shfl_xor(v, m, 64));
  return v;
}
__device__ __forceinline__ void gload_lds16(const void* g, void* l){
  __builtin_amdgcn_global_load_lds(
      (const __attribute__((address_space(1))) uint32*)g,
      (__attribute__((address_space(3))) uint32*)l, 16, 0, 0);
}
__device__ __forceinline__ void load_row16(const float* base, int lane, float* f){
  const float4* s4 = (const float4*)(base + lane * 16);
  float4 t0 = s4[0], t1 = s4[1], t2 = s4[2], t3 = s4[3];
  f[0]=t0.x; f[1]=t0.y; f[2]=t0.z;  f[3]=t0.w;
  f[4]=t1.x; f[5]=t1.y; f[6]=t1.z;  f[7]=t1.w;
  f[8]=t2.x; f[9]=t2.y; f[10]=t2.z; f[11]=t2.w;
  f[12]=t3.x; f[13]=t3.y; f[14]=t3.z; f[15]=t3.w;
}
__device__ __forceinline__ void store_bf16x16(u16* dst_base, int lane, const float* f){
  uint32 pk[8];
  #pragma unroll
  for (int i=0;i<8;++i) pk[i] = (uint32)f2bf(f[2*i]) | ((uint32)f2bf(f[2*i+1]) << 16);
  uint4* d = (uint4*)(dst_base + lane * 16);
  d[0] = make_uint4(pk[0],pk[1],pk[2],pk[3]);
  d[1] = make_uint4(pk[4],pk[5],pk[6],pk[7]);
}

// ------- fused prep: vocab (blocks [0,NVB)) + tokens (blocks [NVB,NVB+512)) ----
// vocab path also writes wlow: compact fp32 [V][32] copy of emb[:, :32].
__global__ void __launch_bounds__(256)
prep_kernel(const float* __restrict__ emb, u16* __restrict__ emb16,
            float* __restrict__ invn_f, float* __restrict__ invn_l,
            float* __restrict__ wlow,
            const float* __restrict__ h, u16* __restrict__ h16,
            float* __restrict__ invh_f, float* __restrict__ invh_l,
            float* __restrict__ hpart, float* __restrict__ out)
{
  const int bid = blockIdx.x;
  const int tid = threadIdx.x, lane = tid & 63, wid = tid >> 6;
  if (bid < NVB){
    if (bid == 0 && tid == 0) out[0] = 0.f;   // zero loss accumulator
    const int v = bid * 4 + wid;
    if (v >= V_SIZE) return;
    float f[16];
    load_row16(emb + (size_t)v * D_DIM, lane, f);
    float ss = 0.f;
    #pragma unroll
    for (int k=0;k<16;++k) ss += f[k]*f[k];
    float fullss = wred_sum(ss);
    float lowss  = wred_sum(lane < 2 ? ss : 0.f);   // lanes 0,1 own elems 0..31
    store_bf16x16(emb16 + (size_t)v * D_DIM, lane, f);
    if (lane < 2){
      float4* wp = (float4*)(wlow + (size_t)v * LOWR + lane * 16);
      wp[0] = make_float4(f[0], f[1], f[2],  f[3]);
      wp[1] = make_float4(f[4], f[5], f[6],  f[7]);
      wp[2] = make_float4(f[8], f[9], f[10], f[11]);
      wp[3] = make_float4(f[12],f[13],f[14], f[15]);
    }
    if (lane == 0){
      invn_f[v] = 1.f / fmaxf(sqrtf(fullss), 1e-12f);
      invn_l[v] = 1.f / fmaxf(sqrtf(lowss),  1e-12f);
    }
    return;
  }
  // token path
  const int bid2 = bid - NVB;
  const int nchunk = bid2 >> 3, sub = bid2 & 7;
  __shared__ float hm[LOWR];
  if (tid < LOWR) hm[tid] = 0.f;
  __syncthreads();
  for (int i = 0; i < 4; ++i){
    const int loc = sub*16 + wid*4 + i;
    const int tok = nchunk * CCHUNK + loc;
    float f[16];
    load_row16(h + (size_t)tok * D_DIM, lane, f);
    float ss = 0.f;
    #pragma unroll
    for (int k=0;k<16;++k) ss += f[k]*f[k];
    float fullss = wred_sum(ss);
    float lowss  = wred_sum(lane < 2 ? ss : 0.f);
    float invf = 1.f / fmaxf(sqrtf(fullss), 1e-12f);
    float invl = 1.f / fmaxf(sqrtf(lowss),  1e-12f);
    store_bf16x16(h16 + (size_t)tok * D_DIM, lane, f);
    if (lane == 0){ invh_f[tok] = invf; invh_l[tok] = invl; }
    if (lane < 2){
      #pragma unroll
      for (int k=0;k<16;++k) atomicAdd(&hm[lane*16 + k], f[k] * invl * (1.f/128.f));
    }
  }
  __syncthreads();
  if (tid < LOWR) hpart[(size_t)(nchunk*8 + sub) * LOWR + tid] = hm[tid];
}

// -------- scan: scan[n][v] = h_mean[n] . (wlow[v] * invn_l[v]) (compact read) --
__global__ void __launch_bounds__(256)
scan_kernel(const float* __restrict__ wlow, const float* __restrict__ invn_l,
            const float* __restrict__ hpart, float* __restrict__ scan)
{
  __shared__ float hm[NCHUNK * LOWR];
  for (int i = threadIdx.x; i < NCHUNK * LOWR; i += 256){
    const int nn = i >> 5, l = i & 31;
    float s = 0.f;
    #pragma unroll
    for (int p = 0; p < 8; ++p) s += hpart[(size_t)(nn*8 + p) * LOWR + l];
    hm[i] = s;
  }
  __syncthreads();
  const int v = blockIdx.x * 256 + threadIdx.x;
  if (v >= V_SIZE){
    if (v < V_PAD)
      for (int nn = 0; nn < NCHUNK; ++nn) scan[(size_t)nn * V_PAD + v] = -3.4e38f;
    return;
  }
  float w[LOWR];
  const float4* s4 = (const float4*)(wlow + (size_t)v * LOWR);
  #pragma unroll
  for (int i=0;i<8;++i){
    float4 t = s4[i];
    w[4*i]=t.x; w[4*i+1]=t.y; w[4*i+2]=t.z; w[4*i+3]=t.w;
  }
  const float inv = invn_l[v];
  #pragma unroll
  for (int i=0;i<LOWR;++i) w[i] *= inv;
  for (int nn = 0; nn < NCHUNK; ++nn){
    float d = 0.f;
    #pragma unroll
    for (int l=0;l<LOWR;++l) d += w[l] * hm[nn*LOWR + l];
    scan[(size_t)nn * V_PAD + v] = d;
  }
}

// ---- single-kernel exact top-K per chunk: 8x-privatized hist + wave-agg lists -
__global__ void __launch_bounds__(1024)
topk_all(const float* __restrict__ scan,
         const float* __restrict__ invn_f, const float* __restrict__ invn_l,
         int* __restrict__ topidx, float* __restrict__ invc_f, float* __restrict__ invc_l)
{
  const int nchunk = blockIdx.x, tid = threadIdx.x, lane = tid & 63;
  __shared__ uint32 h8[8][2048];      // 64 KB privatized 11-bit histograms
  __shared__ int gt_list[2048];       //  8 KB
  __shared__ u64 sd_list[SDCAP];      // 48 KB threshold-bin entries
  __shared__ uint32 rh[256];          //  1 KB refine hist
  __shared__ uint32 n_gt, n_sd, s_tb, s_cgt, s_sel, s_cum, s_pos;
  if (tid == 0){ n_gt = 0; n_sd = 0; s_pos = 0; }
  for (int i = tid; i < 8*2048; i += 1024) (&h8[0][0])[i] = 0;
  __syncthreads();
  const float4* row = (const float4*)(scan + (size_t)nchunk * V_PAD);
  const int cp = (tid >> 6) & 7;
  // pass 1: 11-bit histogram, 8 privatized copies
  for (int i = tid; i < NV4; i += 1024){
    float4 x = row[i];
    atomicAdd(&h8[cp][key_of(x.x) >> 21], 1u);
    atomicAdd(&h8[cp][key_of(x.y) >> 21], 1u);
    atomicAdd(&h8[cp][key_of(x.z) >> 21], 1u);
    atomicAdd(&h8[cp][key_of(x.w) >> 21], 1u);
  }
  __syncthreads();
  for (int i = tid; i < 2048; i += 1024){
    uint32 s = h8[0][i];
    #pragma unroll
    for (int c = 1; c < 8; ++c) s += h8[c][i];
    h8[0][i] = s;
  }
  __syncthreads();
  // threshold: wave 0, coarse 64 groups x 32 bins (descending suffix scans)
  if (tid < 64){
    uint32 c = 0;
    #pragma unroll 8
    for (int k = 0; k < 32; ++k) c += h8[0][lane*32 + k];
    uint32 s = c;
    #pragma unroll
    for (int off = 1; off < 64; off <<= 1){
      uint32 t = __shfl_down(s, off, 64);
      if (lane + off < 64) s += t;
    }
    u64 m1 = __ballot(s >= NCAND);
    const int g = 63 - __builtin_clzll(m1);
    const uint32 cum = (g < 63) ? __shfl(s, g + 1, 64) : 0u;
    uint32 s2 = (lane < 32) ? h8[0][g*32 + lane] : 0u;
    #pragma unroll
    for (int off = 1; off < 32; off <<= 1){
      uint32 t = __shfl_down(s2, off, 64);
      if (lane + off < 32) s2 += t;
    }
    u64 m2 = __ballot((lane < 32) && (cum + s2 >= NCAND));
    const int j = 63 - __builtin_clzll(m2);
    const uint32 cgt = cum + ((j < 31) ? __shfl(s2, j + 1, 64) : 0u);
    if (lane == 0){ s_tb = (uint32)(g*32 + j); s_cgt = cgt; }
  }
  __syncthreads();
  const uint32 tb = s_tb, cgt = s_cgt;
  // pass 2: classify; wave-aggregated appends (1 LDS atomic per wave per hit-group)
  for (int i = tid; i < NV4; i += 1024){
    float4 x = row[i];
    const int vbase = i * 4;
    float vals[4] = {x.x, x.y, x.z, x.w};
    #pragma unroll
    for (int c = 0; c < 4; ++c){
      uint32 u = key_of(vals[c]);
      uint32 b = u >> 21;
      const int v = vbase + c;
      const bool ok = (v < V_SIZE) && (b >= tb);
      const bool is_gt = ok && (b > tb);
      const bool is_sd = ok && (b == tb);
      const u64 mg = __ballot(is_gt);
      if (mg){
        const int ldr = (int)__builtin_ctzll(mg);
        uint32 base = 0;
        if (lane == ldr) base = atomicAdd(&n_gt, (uint32)__popcll(mg));
        base = __shfl(base, ldr, 64);
        if (is_gt){
          uint32 p = base + (uint32)__popcll(mg & ((1ull << lane) - 1ull));
          if (p < 2048u) gt_list[p] = v;
        }
      }
      const u64 ms = __ballot(is_sd);
      if (ms){
        const int ldr = (int)__builtin_ctzll(ms);
        uint32 base = 0;
        if (lane == ldr) base = atomicAdd(&n_sd, (uint32)__popcll(ms));
        base = __shfl(base, ldr, 64);
        if (is_sd){
          uint32 p = base + (uint32)__popcll(ms & ((1ull << lane) - 1ull));
          if (p < (uint32)SDCAP) sd_list[p] = ((u64)(~u) << 32) | (uint32)v;
        }
      }
    }
  }
  __syncthreads();
  // write strictly-greater candidates
  const uint32 ng = n_gt < 2048u ? n_gt : 2048u;
  for (uint32 i = tid; i < ng; i += 1024){
    const int v = gt_list[i];
    const int o = nchunk * NCAND + (int)i;
    topidx[o] = v; invc_f[o] = invn_f[v]; invc_l[o] = invn_l[v];
  }
  // refine: r-th smallest u64; byte 7 constant (same bin), byte 3 always 0.
  const int n = (int)(n_sd < (uint32)SDCAP ? n_sd : (uint32)SDCAP);
  uint32 r = NCAND - cgt; if ((int)r > n) r = (uint32)n;
  u64 pref = sd_list[0] & 0xFF00000000000000ull;
  uint32 rem = r;
  const int bytes6[6] = {6,5,4,2,1,0};
  for (int bi = 0; bi < 6; ++bi){
    const int by = bytes6[bi];
    if (tid < 256) rh[tid] = 0;
    __syncthreads();
    const u64 pmask = (~0ull) << ((by+1)*8);
    for (int i = tid; i < n; i += 1024){
      u64 x = sd_list[i];
      if ((x & pmask) == pref) atomicAdd(&rh[(uint32)(x >> (by*8)) & 255u], 1u);
    }
    __syncthreads();
    if (tid < 64){
      const uint32 b0 = rh[lane*4], b1 = rh[lane*4+1], b2 = rh[lane*4+2], b3 = rh[lane*4+3];
      uint32 ps = b0 + b1 + b2 + b3;
      #pragma unroll
      for (int off = 1; off < 64; off <<= 1){
        uint32 t = __shfl_up(ps, off, 64);
        if (lane >= off) ps += t;
      }
      const u64 mm = __ballot(ps >= rem);
      const int gl = (int)__builtin_ctzll(mm);
      const uint32 before = (gl > 0) ? __shfl(ps, gl-1, 64) : 0u;
      if (lane == gl){
        uint32 cum = before; uint32 bsel = (uint32)gl * 4;
        if (cum + b0 < rem){ cum += b0; bsel++;
          if (cum + b1 < rem){ cum += b1; bsel++;
            if (cum + b2 < rem){ cum += b2; bsel++; } } }
        s_sel = bsel; s_cum = cum;
      }
    }
    __syncthreads();
    pref |= ((u64)s_sel) << (by*8);
    rem -= s_cum;
    __syncthreads();
  }
  for (int i = tid; i < n; i += 1024){
    u64 x = sd_list[i];
    if (x <= pref){
      uint32 p = atomicAdd(&s_pos, 1u);
      const int v = (int)(uint32)x;
      const int o = nchunk * NCAND + (int)(cgt + p);
      topidx[o] = v; invc_f[o] = invn_f[v]; invc_l[o] = invn_l[v];
    }
  }
}

// ------- fused bf16 MFMA GEMM: main (K=1024) + aux (K=32) partial LSEs ---------
// XCD swizzle: id = (chunk&7) + 8*(tile + 16*(chunk>>3)) keeps a chunk's 16
// tiles on one XCD (A-tile + B-gather L2 reuse). LDS swizzle both-sides (#21).
__global__ void __launch_bounds__(256)
gemm_fused(const u16* __restrict__ h16, const u16* __restrict__ emb16,
           const int* __restrict__ topidx,
           const float* __restrict__ invh_f, const float* __restrict__ invc_f,
           const float* __restrict__ invh_l, const float* __restrict__ invc_l,
           const int* __restrict__ tgts, const float* __restrict__ lsc,
           float* __restrict__ pm, float* __restrict__ pa)
{
  constexpr int BK = 64, NSTEP = D_DIM / BK, KK = BK / 32;
  const int id = blockIdx.x;
  const int s_ = id >> 3;
  const int ntile = s_ & 15;
  const int nchunk = ((s_ >> 4) << 3) | (id & 7);
  const int tid = threadIdx.x, lane = tid & 63, wid = tid >> 6;
  const int wm = wid >> 1, wn = wid & 1;
  const int fq = lane >> 4, fr = lane & 15;

  __shared__ u16 As[CCHUNK * BK];
  __shared__ u16 Bs[CCHUNK * BK];
  __shared__ float s_invh[CCHUNK], s_invc[CCHUNK];
  __shared__ float s_invhl[CCHUNK], s_invcl[CCHUNK];
  __shared__ int   s_tgt[CCHUNK], s_idx[CCHUNK];

  if (tid < CCHUNK){
    s_invh[tid]  = invh_f[nchunk * CCHUNK + tid];
    s_invhl[tid] = invh_l[nchunk * CCHUNK + tid];
    s_tgt[tid]   = tgts[nchunk * CCHUNK + tid];
    int o = nchunk * NCAND + ntile * CCHUNK + tid;
    s_idx[tid]   = topidx[o];
    s_invc[tid]  = invc_f[o];
    s_invcl[tid] = invc_l[o];
  }

  // main staging: granule 8 rows x 8 slots of 16B; source slot pre-swizzled
  const int rl = lane >> 3;
  const int cbyte = ((lane & 7) ^ (rl & 7)) * 16;
  const char* aptr[4];
  const char* bptr[4];
  #pragma unroll
  for (int s = 0; s < 4; ++s){
    int row = wid * 32 + s * 8 + rl;
    aptr[s] = (const char*)h16 + ((size_t)(nchunk * CCHUNK + row)) * (D_DIM * 2) + cbyte;
    int cidx = topidx[nchunk * NCAND + ntile * CCHUNK + row];
    bptr[s] = (const char*)emb16 + (size_t)cidx * (D_DIM * 2) + cbyte;
  }

  f32x4 acc[4][4];
  #pragma unroll
  for (int m=0;m<4;++m)
    #pragma unroll
    for (int q=0;q<4;++q)
      acc[m][q] = (f32x4){0.f,0.f,0.f,0.f};

  for (int st = 0; st < NSTEP; ++st){
    const int koff = st * BK * 2;
    #pragma unroll
    for (int s = 0; s < 4; ++s){
      gload_lds16(aptr[s] + koff, (void*)&As[(wid*32 + s*8) * BK]);
      gload_lds16(bptr[s] + koff, (void*)&Bs[(wid*32 + s*8) * BK]);
    }
    __syncthreads();
    #pragma unroll
    for (int kk = 0; kk < KK; ++kk){
      short8 af[4], bf[4];
      #pragma unroll
      for (int m=0;m<4;++m){
        const int r = wm*64 + m*16 + fr, slot = kk*4 + fq;
        af[m] = *(const short8*)&As[r*BK + ((slot ^ (r & 7)) << 3)];
      }
      #pragma unroll
      for (int q=0;q<4;++q){
        const int r = wn*64 + q*16 + fr, slot = kk*4 + fq;
        bf[q] = *(const short8*)&Bs[r*BK + ((slot ^ (r & 7)) << 3)];
      }
      #pragma unroll
      for (int m=0;m<4;++m)
        #pragma unroll
        for (int q=0;q<4;++q)
          acc[m][q] = __builtin_amdgcn_mfma_f32_16x16x32_bf16(af[m], bf[q], acc[m][q], 0, 0, 0);
    }
    __syncthreads();
  }

  // issue aux staging now (first 32 cols); latency hidden by main epilogue
  {
    const int rla = lane >> 2;
    const int cba = ((lane & 3) ^ (rla & 3)) * 16;
    #pragma unroll
    for (int s = 0; s < 2; ++s){
      int row = wid * 32 + s * 16 + rla;
      const char* ap = (const char*)h16 + ((size_t)(nchunk * CCHUNK + row)) * (D_DIM * 2) + cba;
      int cidx = topidx[nchunk * NCAND + ntile * CCHUNK + row];
      const char* bp = (const char*)emb16 + (size_t)cidx * (D_DIM * 2) + cba;
      gload_lds16(ap, (void*)&As[(wid*32 + s*16) * 32]);
      gload_lds16(bp, (void*)&Bs[(wid*32 + s*16) * 32]);
    }
  }

  const float scale = sigscale(lsc);
  const float NEG = -__builtin_huge_valf();

  // main epilogue -> pm
  #pragma unroll
  for (int m=0;m<4;++m){
    #pragma unroll
    for (int j=0;j<4;++j){
      const int c = wm*64 + m*16 + fq*4 + j;
      const float ihs = s_invh[c] * scale;
      const int tg = s_tgt[c];
      float vals[4];
      #pragma unroll
      for (int q=0;q<4;++q){
        const int kl = wn*64 + q*16 + fr;
        float lg = acc[m][q][j] * ihs * s_invc[kl];
        vals[q] = (s_idx[kl] == tg) ? NEG : lg;
      }
      float lmax = fmaxf(fmaxf(vals[0], vals[1]), fmaxf(vals[2], vals[3]));
      #pragma unroll
      for (int ms=1; ms<16; ms<<=1) lmax = fmaxf(lmax, __shfl_xor(lmax, ms, 64));
      float se = 0.f;
      #pragma unroll
      for (int q=0;q<4;++q) se += __expf(vals[q] - lmax);
      #pragma unroll
      for (int ms=1; ms<16; ms<<=1) se += __shfl_xor(se, ms, 64);
      if (fr == 0){
        size_t pos = ((size_t)((nchunk*NTILES + ntile)*2 + wn) * CCHUNK + c) * 2;
        pm[pos]   = lmax;
        pm[pos+1] = se;
      }
    }
  }

  __syncthreads();   // aux staging drained + main LDS reads done

  // aux compute: one MFMA per fragment pair
  f32x4 acc2[4][4];
  {
    short8 afa[4], bfa[4];
    #pragma unroll
    for (int m=0;m<4;++m){
      const int r = wm*64 + m*16 + fr;
      afa[m] = *(const short8*)&As[r*32 + ((fq ^ (r & 3)) << 3)];
    }
    #pragma unroll
    for (int q=0;q<4;++q){
      const int r = wn*64 + q*16 + fr;
      bfa[q] = *(const short8*)&Bs[r*32 + ((fq ^ (r & 3)) << 3)];
    }
    #pragma unroll
    for (int m=0;m<4;++m)
      #pragma unroll
      for (int q=0;q<4;++q)
        acc2[m][q] = __builtin_amdgcn_mfma_f32_16x16x32_bf16(
            afa[m], bfa[q], (f32x4){0.f,0.f,0.f,0.f}, 0, 0, 0);
  }

  // aux epilogue -> pa
  #pragma unroll
  for (int m=0;m<4;++m){
    #pragma unroll
    for (int j=0;j<4;++j){
      const int c = wm*64 + m*16 + fq*4 + j;
      const float ihs = s_invhl[c] * scale;
      const int tg = s_tgt[c];
      float vals[4];
      #pragma unroll
      for (int q=0;q<4;++q){
        const int kl = wn*64 + q*16 + fr;
        float lg = acc2[m][q][j] * ihs * s_invcl[kl];
        vals[q] = (s_idx[kl] == tg) ? NEG : lg;
      }
      float lmax = fmaxf(fmaxf(vals[0], vals[1]), fmaxf(vals[2], vals[3]));
      #pragma unroll
      for (int ms=1; ms<16; ms<<=1) lmax = fmaxf(lmax, __shfl_xor(lmax, ms, 64));
      float se = 0.f;
      #pragma unroll
      for (int q=0;q<4;++q) se += __expf(vals[q] - lmax);
      #pragma unroll
      for (int ms=1; ms<16; ms<<=1) se += __shfl_xor(se, ms, 64);
      if (fr == 0){
        size_t pos = ((size_t)((nchunk*NTILES + ntile)*2 + wn) * CCHUNK + c) * 2;
        pa[pos]   = lmax;
        pa[pos+1] = se;
      }
    }
  }
}

// ---------------- merge partials + target term -> scalar loss ------------------
__global__ void __launch_bounds__(256)
merge_loss(const u16* __restrict__ h16, const u16* __restrict__ emb16,
           const int* __restrict__ tgts,
           const float* __restrict__ invh_f, const float* __restrict__ invh_l,
           const float* __restrict__ invn_f, const float* __restrict__ invn_l,
           const float* __restrict__ pm, const float* __restrict__ pa,
           const float* __restrict__ lsc, float* __restrict__ out)
{
  const int nchunk = blockIdx.x >> 2, quarter = blockIdx.x & 3;
  const int tid = threadIdx.x, lane = tid & 63, wid = tid >> 6;
  const float scale = sigscale(lsc);
  const float NEG = -__builtin_huge_valf();
  float wacc = 0.f;
  for (int i = 0; i < 8; ++i){
    const int loc = quarter*32 + wid*8 + i;
    const int tok = nchunk * CCHUNK + loc;
    const int t = tgts[tok];
    float part = 0.f;
    {
      const uint4* hp = (const uint4*)(h16 + (size_t)tok * D_DIM) + lane*2;
      const uint4* ep = (const uint4*)(emb16 + (size_t)t * D_DIM) + lane*2;
      uint4 hx = hp[0], hy = hp[1], ex = ep[0], ey = ep[1];
      uint32 hu[8] = {hx.x,hx.y,hx.z,hx.w,hy.x,hy.y,hy.z,hy.w};
      uint32 eu[8] = {ex.x,ex.y,ex.z,ex.w,ey.x,ey.y,ey.z,ey.w};
      #pragma unroll
      for (int k=0;k<8;++k){
        float h0 = __uint_as_float(hu[k] << 16);
        float h1 = __uint_as_float(hu[k] & 0xFFFF0000u);
        float e0 = __uint_as_float(eu[k] << 16);
        float e1 = __uint_as_float(eu[k] & 0xFFFF0000u);
        part += h0*e0 + h1*e1;
      }
    }
    float dfull = wred_sum(part);
    float dlow  = wred_sum(lane < 2 ? part : 0.f);
    float tful = dfull * invh_f[tok] * invn_f[t] * scale;
    float tlow = dlow  * invh_l[tok] * invn_l[t] * scale;

    float mi = NEG, si = 0.f, mia = NEG, sia = 0.f;
    if (lane < 32){
      size_t q = ((size_t)(nchunk*32 + lane) * CCHUNK + loc) * 2;
      mi  = pm[q]; si  = pm[q+1];
      mia = pa[q]; sia = pa[q+1];
    }
    float M  = wred_max(mi);
    float S  = wred_sum(lane < 32 ? si * __expf(mi - M) : 0.f);
    float M2 = fmaxf(M, tful);
    float lmain = __logf(S * __expf(M - M2) + __expf(tful - M2)) + M2 - tful;
    float Ma  = wred_max(mia);
    float Sa  = wred_sum(lane < 32 ? sia * __expf(mia - Ma) : 0.f);
    float M2a = fmaxf(Ma, tlow);
    float laux = __logf(Sa * __expf(Ma - M2a) + __expf(tlow - M2a)) + M2a - tlow;
    wacc += lmain + 0.2f * laux;
  }
  __shared__ float ws4[4];
  if (lane == 0) ws4[wid] = wacc;
  __syncthreads();
  if (tid == 0) atomicAdd(out, (ws4[0]+ws4[1]+ws4[2]+ws4[3]) * (1.f / (float)T_TOK));
}

// ---------------- host ---------------------------------------------------------
extern "C" void kernel_launch(void* const* d_in, const int* in_sizes, int n_in,
                              void* d_out, int out_size, void* d_ws, size_t ws_size,
                              hipStream_t stream)
{
  (void)in_sizes; (void)n_in; (void)out_size; (void)ws_size;
  const float* h   = (const float*)d_in[0];
  const float* emb = (const float*)d_in[1];
  const float* lsc = (const float*)d_in[2];
  const int*   tgt = (const int*)d_in[3];
  float* out = (float*)d_out;

  uint8_t* p = (uint8_t*)d_ws;
  auto carve = [&](size_t n)->uint8_t*{
    uint8_t* r = p; p += (n + 255) & ~(size_t)255; return r;
  };
  u16*   emb16  = (u16*)  carve((size_t)V_SIZE * D_DIM * 2);
  float* invn_f = (float*)carve((size_t)V_SIZE * 4);
  float* invn_l = (float*)carve((size_t)V_SIZE * 4);
  float* wlow   = (float*)carve((size_t)V_SIZE * LOWR * 4);
  u16*   h16    = (u16*)  carve((size_t)T_TOK * D_DIM * 2);
  float* invh_f = (float*)carve((size_t)T_TOK * 4);
  float* invh_l = (float*)carve((size_t)T_TOK * 4);
  float* hpart  = (float*)carve((size_t)NCHUNK * 8 * LOWR * 4);
  float* scan   = (float*)carve((size_t)NCHUNK * V_PAD * 4);
  int*   topidx = (int*)  carve((size_t)NCHUNK * NCAND * 4);
  float* invc_f = (float*)carve((size_t)NCHUNK * NCAND * 4);
  float* invc_l = (float*)carve((size_t)NCHUNK * NCAND * 4);
  float* pm     = (float*)carve((size_t)NCHUNK * 32 * CCHUNK * 2 * 4);
  float* pa     = (float*)carve((size_t)NCHUNK * 32 * CCHUNK * 2 * 4);

  prep_kernel<<<dim3(NVB + NCHUNK*8), dim3(256), 0, stream>>>(
      emb, emb16, invn_f, invn_l, wlow, h, h16, invh_f, invh_l, hpart, out);
  scan_kernel<<<dim3(V_PAD / 256), dim3(256), 0, stream>>>(wlow, invn_l, hpart, scan);
  topk_all<<<dim3(NCHUNK), dim3(1024), 0, stream>>>(
      scan, invn_f, invn_l, topidx, invc_f, invc_l);
  gemm_fused<<<dim3(NTILES * NCHUNK), dim3(256), 0, stream>>>(
      h16, emb16, topidx, invh_f, invc_f, invh_l, invc_l, tgt, lsc, pm, pa);
  merge_loss<<<dim3(NCHUNK * 4), dim3(256), 0, stream>>>(
      h16, emb16, tgt, invh_f, invh_l, invn_f, invn_l, pm, pa, lsc, out);
}

// Round 7
// 192.087 us; speedup vs baseline: 2.6894x; 1.1069x over previous
//
#include <hip/hip_runtime.h>
#include <cstdint>
#include <cstddef>

#define V_SIZE 50257
#define V_PAD  50432
#define NV4    (V_PAD/4)
#define NVB    ((V_SIZE + 3) / 4)
#define D_DIM  1024
#define T_TOK  8192
#define NCHUNK 64
#define CCHUNK 128
#define NCAND  2048
#define NTILES 16
#define LOWR   32
#define SDCAP  6144
#define ESCALE 32.0f   // emb pre-scale before fp8 (power of 2; folded out in epilogue)

typedef unsigned int  uint32;
typedef unsigned short u16;
typedef unsigned char u8;
typedef unsigned long long u64;
typedef __attribute__((ext_vector_type(8))) short short8;
typedef __attribute__((ext_vector_type(4))) float f32x4;

__device__ __forceinline__ u16 f2bf(float f){
  uint32 u = __float_as_uint(f);
  return (u16)((u + 0x7FFFu + ((u >> 16) & 1u)) >> 16);
}
__device__ __forceinline__ uint32 key_of(float f){
  uint32 b = __float_as_uint(f);
  return b ^ ((uint32)((int)b >> 31) | 0x80000000u);
}
__device__ __forceinline__ float sigscale(const float* lsc){
  return 100.f / (1.f + __expf(-lsc[0])) + 1.f;
}
__device__ __forceinline__ float wred_sum(float v){
  #pragma unroll
  for (int m = 32; m >= 1; m >>= 1) v += __shfl_xor(v, m, 64);
  return v;
}
__device__ __forceinline__ float wred_max(float v){
  #pragma unroll
  for (int m = 32; m >= 1; m >>= 1) v = fmaxf(v, __shfl_xor(v, m, 64));
  return v;
}
__device__ __forceinline__ void gload_lds16(const void* g, void* l){
  __builtin_amdgcn_global_load_lds(
      (const __attribute__((address_space(1))) uint32*)g,
      (__attribute__((address_space(3))) uint32*)l, 16, 0, 0);
}
__device__ __forceinline__ void load_row16(const float* base, int lane, float* f){
  const float4* s4 = (const float4*)(base + lane * 16);
  float4 t0 = s4[0], t1 = s4[1], t2 = s4[2], t3 = s4[3];
  f[0]=t0.x; f[1]=t0.y; f[2]=t0.z;  f[3]=t0.w;
  f[4]=t1.x; f[5]=t1.y; f[6]=t1.z;  f[7]=t1.w;
  f[8]=t2.x; f[9]=t2.y; f[10]=t2.z; f[11]=t2.w;
  f[12]=t3.x; f[13]=t3.y; f[14]=t3.z; f[15]=t3.w;
}
__device__ __forceinline__ void store_bf16x16(u16* dst_base, int lane, const float* f){
  uint32 pk[8];
  #pragma unroll
  for (int i=0;i<8;++i) pk[i] = (uint32)f2bf(f[2*i]) | ((uint32)f2bf(f[2*i+1]) << 16);
  uint4* d = (uint4*)(dst_base + lane * 16);
  d[0] = make_uint4(pk[0],pk[1],pk[2],pk[3]);
  d[1] = make_uint4(pk[4],pk[5],pk[6],pk[7]);
}
__device__ __forceinline__ void store_fp8x16(u8* dst_base, int lane, const float* f, float sc){
  uint32 pk[4];
  #pragma unroll
  for (int i=0;i<4;++i){
    int w = __builtin_amdgcn_cvt_pk_fp8_f32(f[4*i]*sc,   f[4*i+1]*sc, 0, false);
    w     = __builtin_amdgcn_cvt_pk_fp8_f32(f[4*i+2]*sc, f[4*i+3]*sc, w, true);
    pk[i] = (uint32)w;
  }
  *(uint4*)(dst_base + lane * 16) = make_uint4(pk[0],pk[1],pk[2],pk[3]);
}
// fp8 fragment read address within a 64B-row LDS tile (both-sides 16B XOR swizzle)
__device__ __forceinline__ int a8(int r, int slot8){
  return r*64 + ((((slot8>>1) ^ (r&3))) << 4) + ((slot8&1) << 3);
}

// ------- fused prep: vocab (blocks [0,NVB)) + tokens (blocks [NVB,NVB+512)) ----
__global__ void __launch_bounds__(256)
prep_kernel(const float* __restrict__ emb, u8* __restrict__ emb8,
            u16* __restrict__ elow16,
            float* __restrict__ invn_f, float* __restrict__ invn_l,
            float* __restrict__ wlow,
            const float* __restrict__ h, u8* __restrict__ h8,
            u16* __restrict__ hlow16,
            float* __restrict__ invh_f, float* __restrict__ invh_l,
            float* __restrict__ hpart, float* __restrict__ out)
{
  const int bid = blockIdx.x;
  const int tid = threadIdx.x, lane = tid & 63, wid = tid >> 6;
  if (bid < NVB){
    if (bid == 0 && tid == 0) out[0] = 0.f;   // zero loss accumulator
    const int v = bid * 4 + wid;
    if (v >= V_SIZE) return;
    float f[16];
    load_row16(emb + (size_t)v * D_DIM, lane, f);
    float ss = 0.f;
    #pragma unroll
    for (int k=0;k<16;++k) ss += f[k]*f[k];
    float fullss = wred_sum(ss);
    float lowss  = wred_sum(lane < 2 ? ss : 0.f);   // lanes 0,1 own elems 0..31
    store_fp8x16(emb8 + (size_t)v * D_DIM, lane, f, ESCALE);
    if (lane < 2){
      store_bf16x16(elow16 + (size_t)v * LOWR, lane, f);
      float4* wp = (float4*)(wlow + (size_t)v * LOWR + lane * 16);
      wp[0] = make_float4(f[0], f[1], f[2],  f[3]);
      wp[1] = make_float4(f[4], f[5], f[6],  f[7]);
      wp[2] = make_float4(f[8], f[9], f[10], f[11]);
      wp[3] = make_float4(f[12],f[13],f[14], f[15]);
    }
    if (lane == 0){
      invn_f[v] = 1.f / fmaxf(sqrtf(fullss), 1e-12f);
      invn_l[v] = 1.f / fmaxf(sqrtf(lowss),  1e-12f);
    }
    return;
  }
  // token path
  const int bid2 = bid - NVB;
  const int nchunk = bid2 >> 3, sub = bid2 & 7;
  __shared__ float hm[LOWR];
  if (tid < LOWR) hm[tid] = 0.f;
  __syncthreads();
  for (int i = 0; i < 4; ++i){
    const int loc = sub*16 + wid*4 + i;
    const int tok = nchunk * CCHUNK + loc;
    float f[16];
    load_row16(h + (size_t)tok * D_DIM, lane, f);
    float ss = 0.f;
    #pragma unroll
    for (int k=0;k<16;++k) ss += f[k]*f[k];
    float fullss = wred_sum(ss);
    float lowss  = wred_sum(lane < 2 ? ss : 0.f);
    float invf = 1.f / fmaxf(sqrtf(fullss), 1e-12f);
    float invl = 1.f / fmaxf(sqrtf(lowss),  1e-12f);
    store_fp8x16(h8 + (size_t)tok * D_DIM, lane, f, 1.0f);
    if (lane < 2) store_bf16x16(hlow16 + (size_t)tok * LOWR, lane, f);
    if (lane == 0){ invh_f[tok] = invf; invh_l[tok] = invl; }
    if (lane < 2){
      #pragma unroll
      for (int k=0;k<16;++k) atomicAdd(&hm[lane*16 + k], f[k] * invl * (1.f/128.f));
    }
  }
  __syncthreads();
  if (tid < LOWR) hpart[(size_t)(nchunk*8 + sub) * LOWR + tid] = hm[tid];
}

// -------- scan: scan[n][v] = h_mean[n] . (wlow[v] * invn_l[v]) (compact read) --
__global__ void __launch_bounds__(256)
scan_kernel(const float* __restrict__ wlow, const float* __restrict__ invn_l,
            const float* __restrict__ hpart, float* __restrict__ scan)
{
  __shared__ float hm[NCHUNK * LOWR];
  for (int i = threadIdx.x; i < NCHUNK * LOWR; i += 256){
    const int nn = i >> 5, l = i & 31;
    float s = 0.f;
    #pragma unroll
    for (int p = 0; p < 8; ++p) s += hpart[(size_t)(nn*8 + p) * LOWR + l];
    hm[i] = s;
  }
  __syncthreads();
  const int v = blockIdx.x * 256 + threadIdx.x;
  if (v >= V_SIZE){
    if (v < V_PAD)
      for (int nn = 0; nn < NCHUNK; ++nn) scan[(size_t)nn * V_PAD + v] = -3.4e38f;
    return;
  }
  float w[LOWR];
  const float4* s4 = (const float4*)(wlow + (size_t)v * LOWR);
  #pragma unroll
  for (int i=0;i<8;++i){
    float4 t = s4[i];
    w[4*i]=t.x; w[4*i+1]=t.y; w[4*i+2]=t.z; w[4*i+3]=t.w;
  }
  const float inv = invn_l[v];
  #pragma unroll
  for (int i=0;i<LOWR;++i) w[i] *= inv;
  for (int nn = 0; nn < NCHUNK; ++nn){
    float d = 0.f;
    #pragma unroll
    for (int l=0;l<LOWR;++l) d += w[l] * hm[nn*LOWR + l];
    scan[(size_t)nn * V_PAD + v] = d;
  }
}

// ---- single-kernel exact top-K per chunk: 8x-privatized hist + wave-agg lists -
__global__ void __launch_bounds__(1024)
topk_all(const float* __restrict__ scan,
         const float* __restrict__ invn_f, const float* __restrict__ invn_l,
         int* __restrict__ topidx, float* __restrict__ invc_f, float* __restrict__ invc_l)
{
  const int nchunk = blockIdx.x, tid = threadIdx.x, lane = tid & 63;
  __shared__ uint32 h8v[8][2048];
  __shared__ int gt_list[2048];
  __shared__ u64 sd_list[SDCAP];
  __shared__ uint32 rh[256];
  __shared__ uint32 n_gt, n_sd, s_tb, s_cgt, s_sel, s_cum, s_pos;
  if (tid == 0){ n_gt = 0; n_sd = 0; s_pos = 0; }
  for (int i = tid; i < 8*2048; i += 1024) (&h8v[0][0])[i] = 0;
  __syncthreads();
  const float4* row = (const float4*)(scan + (size_t)nchunk * V_PAD);
  const int cp = (tid >> 6) & 7;
  for (int i = tid; i < NV4; i += 1024){
    float4 x = row[i];
    atomicAdd(&h8v[cp][key_of(x.x) >> 21], 1u);
    atomicAdd(&h8v[cp][key_of(x.y) >> 21], 1u);
    atomicAdd(&h8v[cp][key_of(x.z) >> 21], 1u);
    atomicAdd(&h8v[cp][key_of(x.w) >> 21], 1u);
  }
  __syncthreads();
  for (int i = tid; i < 2048; i += 1024){
    uint32 s = h8v[0][i];
    #pragma unroll
    for (int c = 1; c < 8; ++c) s += h8v[c][i];
    h8v[0][i] = s;
  }
  __syncthreads();
  if (tid < 64){
    uint32 c = 0;
    #pragma unroll 8
    for (int k = 0; k < 32; ++k) c += h8v[0][lane*32 + k];
    uint32 s = c;
    #pragma unroll
    for (int off = 1; off < 64; off <<= 1){
      uint32 t = __shfl_down(s, off, 64);
      if (lane + off < 64) s += t;
    }
    u64 m1 = __ballot(s >= NCAND);
    const int g = 63 - __builtin_clzll(m1);
    const uint32 cum = (g < 63) ? __shfl(s, g + 1, 64) : 0u;
    uint32 s2 = (lane < 32) ? h8v[0][g*32 + lane] : 0u;
    #pragma unroll
    for (int off = 1; off < 32; off <<= 1){
      uint32 t = __shfl_down(s2, off, 64);
      if (lane + off < 32) s2 += t;
    }
    u64 m2 = __ballot((lane < 32) && (cum + s2 >= NCAND));
    const int j = 63 - __builtin_clzll(m2);
    const uint32 cgt = cum + ((j < 31) ? __shfl(s2, j + 1, 64) : 0u);
    if (lane == 0){ s_tb = (uint32)(g*32 + j); s_cgt = cgt; }
  }
  __syncthreads();
  const uint32 tb = s_tb, cgt = s_cgt;
  for (int i = tid; i < NV4; i += 1024){
    float4 x = row[i];
    const int vbase = i * 4;
    float vals[4] = {x.x, x.y, x.z, x.w};
    #pragma unroll
    for (int c = 0; c < 4; ++c){
      uint32 u = key_of(vals[c]);
      uint32 b = u >> 21;
      const int v = vbase + c;
      const bool ok = (v < V_SIZE) && (b >= tb);
      const bool is_gt = ok && (b > tb);
      const bool is_sd = ok && (b == tb);
      const u64 mg = __ballot(is_gt);
      if (mg){
        const int ldr = (int)__builtin_ctzll(mg);
        uint32 base = 0;
        if (lane == ldr) base = atomicAdd(&n_gt, (uint32)__popcll(mg));
        base = __shfl(base, ldr, 64);
        if (is_gt){
          uint32 p = base + (uint32)__popcll(mg & ((1ull << lane) - 1ull));
          if (p < 2048u) gt_list[p] = v;
        }
      }
      const u64 ms = __ballot(is_sd);
      if (ms){
        const int ldr = (int)__builtin_ctzll(ms);
        uint32 base = 0;
        if (lane == ldr) base = atomicAdd(&n_sd, (uint32)__popcll(ms));
        base = __shfl(base, ldr, 64);
        if (is_sd){
          uint32 p = base + (uint32)__popcll(ms & ((1ull << lane) - 1ull));
          if (p < (uint32)SDCAP) sd_list[p] = ((u64)(~u) << 32) | (uint32)v;
        }
      }
    }
  }
  __syncthreads();
  const uint32 ng = n_gt < 2048u ? n_gt : 2048u;
  for (uint32 i = tid; i < ng; i += 1024){
    const int v = gt_list[i];
    const int o = nchunk * NCAND + (int)i;
    topidx[o] = v; invc_f[o] = invn_f[v]; invc_l[o] = invn_l[v];
  }
  const int n = (int)(n_sd < (uint32)SDCAP ? n_sd : (uint32)SDCAP);
  uint32 r = NCAND - cgt; if ((int)r > n) r = (uint32)n;
  u64 pref = sd_list[0] & 0xFF00000000000000ull;
  uint32 rem = r;
  const int bytes6[6] = {6,5,4,2,1,0};
  for (int bi = 0; bi < 6; ++bi){
    const int by = bytes6[bi];
    if (tid < 256) rh[tid] = 0;
    __syncthreads();
    const u64 pmask = (~0ull) << ((by+1)*8);
    for (int i = tid; i < n; i += 1024){
      u64 x = sd_list[i];
      if ((x & pmask) == pref) atomicAdd(&rh[(uint32)(x >> (by*8)) & 255u], 1u);
    }
    __syncthreads();
    if (tid < 64){
      const uint32 b0 = rh[lane*4], b1 = rh[lane*4+1], b2 = rh[lane*4+2], b3 = rh[lane*4+3];
      uint32 ps = b0 + b1 + b2 + b3;
      #pragma unroll
      for (int off = 1; off < 64; off <<= 1){
        uint32 t = __shfl_up(ps, off, 64);
        if (lane >= off) ps += t;
      }
      const u64 mm = __ballot(ps >= rem);
      const int gl = (int)__builtin_ctzll(mm);
      const uint32 before = (gl > 0) ? __shfl(ps, gl-1, 64) : 0u;
      if (lane == gl){
        uint32 cum = before; uint32 bsel = (uint32)gl * 4;
        if (cum + b0 < rem){ cum += b0; bsel++;
          if (cum + b1 < rem){ cum += b1; bsel++;
            if (cum + b2 < rem){ cum += b2; bsel++; } } }
        s_sel = bsel; s_cum = cum;
      }
    }
    __syncthreads();
    pref |= ((u64)s_sel) << (by*8);
    rem -= s_cum;
    __syncthreads();
  }
  for (int i = tid; i < n; i += 1024){
    u64 x = sd_list[i];
    if (x <= pref){
      uint32 p = atomicAdd(&s_pos, 1u);
      const int v = (int)(uint32)x;
      const int o = nchunk * NCAND + (int)(cgt + p);
      topidx[o] = v; invc_f[o] = invn_f[v]; invc_l[o] = invn_l[v];
    }
  }
}

// ------- fused GEMM: main fp8 (K=1024, emb pre-scaled x32) + aux bf16 (K=32) ---
__global__ void __launch_bounds__(256)
gemm_fused(const u8* __restrict__ h8, const u8* __restrict__ emb8,
           const u16* __restrict__ hlow16, const u16* __restrict__ elow16,
           const int* __restrict__ topidx,
           const float* __restrict__ invh_f, const float* __restrict__ invc_f,
           const float* __restrict__ invh_l, const float* __restrict__ invc_l,
           const int* __restrict__ tgts, const float* __restrict__ lsc,
           float* __restrict__ pm, float* __restrict__ pa)
{
  constexpr int NSTEP = 16;   // 1024 / 64
  const int id = blockIdx.x;
  const int s_ = id >> 3;
  const int ntile = s_ & 15;
  const int nchunk = ((s_ >> 4) << 3) | (id & 7);
  const int tid = threadIdx.x, lane = tid & 63, wid = tid >> 6;
  const int wm = wid >> 1, wn = wid & 1;
  const int fq = lane >> 4, fr = lane & 15;

  __shared__ u8 As[CCHUNK * 64];   // 8 KB (fp8 main; reused as bf16x32 for aux)
  __shared__ u8 Bs[CCHUNK * 64];
  __shared__ float s_invh[CCHUNK], s_invc[CCHUNK];
  __shared__ float s_invhl[CCHUNK], s_invcl[CCHUNK];
  __shared__ int   s_tgt[CCHUNK], s_idx[CCHUNK];

  if (tid < CCHUNK){
    s_invh[tid]  = invh_f[nchunk * CCHUNK + tid];
    s_invhl[tid] = invh_l[nchunk * CCHUNK + tid];
    s_tgt[tid]   = tgts[nchunk * CCHUNK + tid];
    int o = nchunk * NCAND + ntile * CCHUNK + tid;
    s_idx[tid]   = topidx[o];
    s_invc[tid]  = invc_f[o];
    s_invcl[tid] = invc_l[o];
  }

  // staging geometry (64B rows): 16 rows per call, 2 calls per wave per matrix
  const int rl = lane >> 2;
  const int cbyte = ((lane & 3) ^ (rl & 3)) * 16;   // pre-swizzled source slot
  const char* aptr[2];
  const char* bptr[2];
  #pragma unroll
  for (int s = 0; s < 2; ++s){
    int row = wid * 32 + s * 16 + rl;
    aptr[s] = (const char*)h8 + ((size_t)(nchunk * CCHUNK + row)) * D_DIM + cbyte;
    int cidx = topidx[nchunk * NCAND + ntile * CCHUNK + row];
    bptr[s] = (const char*)emb8 + (size_t)cidx * D_DIM + cbyte;
  }

  f32x4 acc[4][4];
  #pragma unroll
  for (int m=0;m<4;++m)
    #pragma unroll
    for (int q=0;q<4;++q)
      acc[m][q] = (f32x4){0.f,0.f,0.f,0.f};

  for (int st = 0; st < NSTEP; ++st){
    const int koff = st * 64;
    #pragma unroll
    for (int s = 0; s < 2; ++s){
      gload_lds16(aptr[s] + koff, (void*)&As[(wid*32 + s*16) * 64]);
      gload_lds16(bptr[s] + koff, (void*)&Bs[(wid*32 + s*16) * 64]);
    }
    __syncthreads();
    #pragma unroll
    for (int kk = 0; kk < 2; ++kk){
      long af[4], bf[4];
      #pragma unroll
      for (int m=0;m<4;++m)
        af[m] = *(const long*)&As[a8(wm*64 + m*16 + fr, kk*4 + fq)];
      #pragma unroll
      for (int q=0;q<4;++q)
        bf[q] = *(const long*)&Bs[a8(wn*64 + q*16 + fr, kk*4 + fq)];
      #pragma unroll
      for (int m=0;m<4;++m)
        #pragma unroll
        for (int q=0;q<4;++q)
          acc[m][q] = __builtin_amdgcn_mfma_f32_16x16x32_fp8_fp8(af[m], bf[q], acc[m][q], 0, 0, 0);
    }
    __syncthreads();
  }

  // issue aux staging now (bf16 low-32 tables; 64B rows, same geometry)
  {
    #pragma unroll
    for (int s = 0; s < 2; ++s){
      int row = wid * 32 + s * 16 + rl;
      const char* ap = (const char*)hlow16 + ((size_t)(nchunk * CCHUNK + row)) * (LOWR*2) + cbyte;
      int cidx = topidx[nchunk * NCAND + ntile * CCHUNK + row];
      const char* bp = (const char*)elow16 + (size_t)cidx * (LOWR*2) + cbyte;
      gload_lds16(ap, (void*)&As[(wid*32 + s*16) * 64]);
      gload_lds16(bp, (void*)&Bs[(wid*32 + s*16) * 64]);
    }
  }

  const float scale = sigscale(lsc);
  const float scm = scale * (1.0f / ESCALE);   // undo emb pre-scale (main only)
  const float NEG = -__builtin_huge_valf();

  // main epilogue -> pm
  #pragma unroll
  for (int m=0;m<4;++m){
    #pragma unroll
    for (int j=0;j<4;++j){
      const int c = wm*64 + m*16 + fq*4 + j;
      const float ihs = s_invh[c] * scm;
      const int tg = s_tgt[c];
      float vals[4];
      #pragma unroll
      for (int q=0;q<4;++q){
        const int kl = wn*64 + q*16 + fr;
        float lg = acc[m][q][j] * ihs * s_invc[kl];
        vals[q] = (s_idx[kl] == tg) ? NEG : lg;
      }
      float lmax = fmaxf(fmaxf(vals[0], vals[1]), fmaxf(vals[2], vals[3]));
      #pragma unroll
      for (int ms=1; ms<16; ms<<=1) lmax = fmaxf(lmax, __shfl_xor(lmax, ms, 64));
      float se = 0.f;
      #pragma unroll
      for (int q=0;q<4;++q) se += __expf(vals[q] - lmax);
      #pragma unroll
      for (int ms=1; ms<16; ms<<=1) se += __shfl_xor(se, ms, 64);
      if (fr == 0){
        size_t pos = ((size_t)((nchunk*NTILES + ntile)*2 + wn) * CCHUNK + c) * 2;
        pm[pos]   = lmax;
        pm[pos+1] = se;
      }
    }
  }

  __syncthreads();   // aux staging drained + main LDS reads done

  // aux compute (bf16): one MFMA per fragment pair; 64B rows, 16B slot16 = fq
  f32x4 acc2[4][4];
  {
    short8 afa[4], bfa[4];
    #pragma unroll
    for (int m=0;m<4;++m){
      const int r = wm*64 + m*16 + fr;
      afa[m] = *(const short8*)&As[r*64 + ((fq ^ (r & 3)) << 4)];
    }
    #pragma unroll
    for (int q=0;q<4;++q){
      const int r = wn*64 + q*16 + fr;
      bfa[q] = *(const short8*)&Bs[r*64 + ((fq ^ (r & 3)) << 4)];
    }
    #pragma unroll
    for (int m=0;m<4;++m)
      #pragma unroll
      for (int q=0;q<4;++q)
        acc2[m][q] = __builtin_amdgcn_mfma_f32_16x16x32_bf16(
            afa[m], bfa[q], (f32x4){0.f,0.f,0.f,0.f}, 0, 0, 0);
  }

  // aux epilogue -> pa
  #pragma unroll
  for (int m=0;m<4;++m){
    #pragma unroll
    for (int j=0;j<4;++j){
      const int c = wm*64 + m*16 + fq*4 + j;
      const float ihs = s_invhl[c] * scale;
      const int tg = s_tgt[c];
      float vals[4];
      #pragma unroll
      for (int q=0;q<4;++q){
        const int kl = wn*64 + q*16 + fr;
        float lg = acc2[m][q][j] * ihs * s_invcl[kl];
        vals[q] = (s_idx[kl] == tg) ? NEG : lg;
      }
      float lmax = fmaxf(fmaxf(vals[0], vals[1]), fmaxf(vals[2], vals[3]));
      #pragma unroll
      for (int ms=1; ms<16; ms<<=1) lmax = fmaxf(lmax, __shfl_xor(lmax, ms, 64));
      float se = 0.f;
      #pragma unroll
      for (int q=0;q<4;++q) se += __expf(vals[q] - lmax);
      #pragma unroll
      for (int ms=1; ms<16; ms<<=1) se += __shfl_xor(se, ms, 64);
      if (fr == 0){
        size_t pos = ((size_t)((nchunk*NTILES + ntile)*2 + wn) * CCHUNK + c) * 2;
        pa[pos]   = lmax;
        pa[pos+1] = se;
      }
    }
  }
}

// ---- merge partials + fp32 target term -> scalar loss -------------------------
__global__ void __launch_bounds__(256)
merge_loss(const float* __restrict__ h, const float* __restrict__ emb,
           const int* __restrict__ tgts,
           const float* __restrict__ invh_f, const float* __restrict__ invh_l,
           const float* __restrict__ invn_f, const float* __restrict__ invn_l,
           const float* __restrict__ pm, const float* __restrict__ pa,
           const float* __restrict__ lsc, float* __restrict__ out)
{
  const int nchunk = blockIdx.x >> 2, quarter = blockIdx.x & 3;
  const int tid = threadIdx.x, lane = tid & 63, wid = tid >> 6;
  const float scale = sigscale(lsc);
  const float NEG = -__builtin_huge_valf();
  float wacc = 0.f;
  for (int i = 0; i < 8; ++i){
    const int loc = quarter*32 + wid*8 + i;
    const int tok = nchunk * CCHUNK + loc;
    const int t = tgts[tok];
    float hf[16], ef[16];
    load_row16(h + (size_t)tok * D_DIM, lane, hf);
    load_row16(emb + (size_t)t * D_DIM, lane, ef);
    float part = 0.f;
    #pragma unroll
    for (int k=0;k<16;++k) part += hf[k]*ef[k];
    float dfull = wred_sum(part);
    float dlow  = wred_sum(lane < 2 ? part : 0.f);
    float tful = dfull * invh_f[tok] * invn_f[t] * scale;
    float tlow = dlow  * invh_l[tok] * invn_l[t] * scale;

    float mi = NEG, si = 0.f, mia = NEG, sia = 0.f;
    if (lane < 32){
      size_t q = ((size_t)(nchunk*32 + lane) * CCHUNK + loc) * 2;
      mi  = pm[q]; si  = pm[q+1];
      mia = pa[q]; sia = pa[q+1];
    }
    float M  = wred_max(mi);
    float S  = wred_sum(lane < 32 ? si * __expf(mi - M) : 0.f);
    float M2 = fmaxf(M, tful);
    float lmain = __logf(S * __expf(M - M2) + __expf(tful - M2)) + M2 - tful;
    float Ma  = wred_max(mia);
    float Sa  = wred_sum(lane < 32 ? sia * __expf(mia - Ma) : 0.f);
    float M2a = fmaxf(Ma, tlow);
    float laux = __logf(Sa * __expf(Ma - M2a) + __expf(tlow - M2a)) + M2a - tlow;
    wacc += lmain + 0.2f * laux;
  }
  __shared__ float ws4[4];
  if (lane == 0) ws4[wid] = wacc;
  __syncthreads();
  if (tid == 0) atomicAdd(out, (ws4[0]+ws4[1]+ws4[2]+ws4[3]) * (1.f / (float)T_TOK));
}

// ---------------- host ---------------------------------------------------------
extern "C" void kernel_launch(void* const* d_in, const int* in_sizes, int n_in,
                              void* d_out, int out_size, void* d_ws, size_t ws_size,
                              hipStream_t stream)
{
  (void)in_sizes; (void)n_in; (void)out_size; (void)ws_size;
  const float* h   = (const float*)d_in[0];
  const float* emb = (const float*)d_in[1];
  const float* lsc = (const float*)d_in[2];
  const int*   tgt = (const int*)d_in[3];
  float* out = (float*)d_out;

  uint8_t* p = (uint8_t*)d_ws;
  auto carve = [&](size_t n)->uint8_t*{
    uint8_t* r = p; p += (n + 255) & ~(size_t)255; return r;
  };
  u8*    emb8   = (u8*)   carve((size_t)V_SIZE * D_DIM);
  u16*   elow16 = (u16*)  carve((size_t)V_SIZE * LOWR * 2);
  float* invn_f = (float*)carve((size_t)V_SIZE * 4);
  float* invn_l = (float*)carve((size_t)V_SIZE * 4);
  float* wlow   = (float*)carve((size_t)V_SIZE * LOWR * 4);
  u8*    h8     = (u8*)   carve((size_t)T_TOK * D_DIM);
  u16*   hlow16 = (u16*)  carve((size_t)T_TOK * LOWR * 2);
  float* invh_f = (float*)carve((size_t)T_TOK * 4);
  float* invh_l = (float*)carve((size_t)T_TOK * 4);
  float* hpart  = (float*)carve((size_t)NCHUNK * 8 * LOWR * 4);
  float* scan   = (float*)carve((size_t)NCHUNK * V_PAD * 4);
  int*   topidx = (int*)  carve((size_t)NCHUNK * NCAND * 4);
  float* invc_f = (float*)carve((size_t)NCHUNK * NCAND * 4);
  float* invc_l = (float*)carve((size_t)NCHUNK * NCAND * 4);
  float* pm     = (float*)carve((size_t)NCHUNK * 32 * CCHUNK * 2 * 4);
  float* pa     = (float*)carve((size_t)NCHUNK * 32 * CCHUNK * 2 * 4);

  prep_kernel<<<dim3(NVB + NCHUNK*8), dim3(256), 0, stream>>>(
      emb, emb8, elow16, invn_f, invn_l, wlow, h, h8, hlow16, invh_f, invh_l, hpart, out);
  scan_kernel<<<dim3(V_PAD / 256), dim3(256), 0, stream>>>(wlow, invn_l, hpart, scan);
  topk_all<<<dim3(NCHUNK), dim3(1024), 0, stream>>>(
      scan, invn_f, invn_l, topidx, invc_f, invc_l);
  gemm_fused<<<dim3(NTILES * NCHUNK), dim3(256), 0, stream>>>(
      h8, emb8, hlow16, elow16, topidx, invh_f, invc_f, invh_l, invc_l, tgt, lsc, pm, pa);
  merge_loss<<<dim3(NCHUNK * 4), dim3(256), 0, stream>>>(
      h, emb, tgt, invh_f, invh_l, invn_f, invn_l, pm, pa, lsc, out);
}